// Round 3
// baseline (736.977 us; speedup 1.0000x reference)
//
#include <hip/hip_runtime.h>
#include <hip/hip_bf16.h>

typedef __attribute__((ext_vector_type(8))) short short8;
typedef __attribute__((ext_vector_type(4))) float f32x4;

__device__ __forceinline__ float gelu_exact(float x) {
    return 0.5f * x * (1.0f + erff(x * 0.70710678118654752f));
}
__device__ __forceinline__ float us2f(unsigned int u) {
    return __uint_as_float(u << 16);
}
__device__ __forceinline__ unsigned short f2b_raw(float f) {
    __hip_bfloat16 h = __float2bfloat16(f);
    return *reinterpret_cast<unsigned short*>(&h);
}
__device__ __forceinline__ float tofloat(float f) { return f; }
__device__ __forceinline__ float tofloat(__hip_bfloat16 h) { return __bfloat162float(h); }

// ---------------- conv 3x3 (C=1) + exact GELU over 32x32 patches ----------------
// x: [B*N, 1024] fp32.  Outputs q,k,v in [B*H, N, 128] bf16 layout.
__global__ __launch_bounds__(256) void conv_qkv(
    const float* __restrict__ x,
    const float* __restrict__ qw, const float* __restrict__ kw, const float* __restrict__ vw,
    __hip_bfloat16* __restrict__ qb, __hip_bfloat16* __restrict__ kb, __hip_bfloat16* __restrict__ vb)
{
    __shared__ float img[1024];
    const int bid = blockIdx.x;            // b*1024 + n
    const int b = bid >> 10, n = bid & 1023;
    const float* xr = x + (long)bid * 1024;
    for (int i = threadIdx.x; i < 1024; i += 256) img[i] = xr[i];
    __syncthreads();

    float wq[9], wk[9], wv[9];
    #pragma unroll
    for (int i = 0; i < 9; ++i) { wq[i] = qw[i]; wk[i] = kw[i]; wv[i] = vw[i]; }

    for (int q = 0; q < 4; ++q) {
        const int p = q * 256 + threadIdx.x;    // 0..1023 spatial
        const int r = p >> 5, c = p & 31;
        float sq = 0.f, sk = 0.f, sv = 0.f;
        #pragma unroll
        for (int dy = 0; dy < 3; ++dy) {
            const int rr = r + dy - 1;
            if (rr < 0 || rr > 31) continue;
            #pragma unroll
            for (int dx = 0; dx < 3; ++dx) {
                const int cc = c + dx - 1;
                if (cc < 0 || cc > 31) continue;
                const float px = img[rr * 32 + cc];
                sq += px * wq[dy * 3 + dx];
                sk += px * wk[dy * 3 + dx];
                sv += px * wv[dy * 3 + dx];
            }
        }
        sq = gelu_exact(sq); sk = gelu_exact(sk); sv = gelu_exact(sv);
        const int h = p >> 7, d = p & 127;
        const long off = ((long)(b * 8 + h) * 1024 + n) * 128 + d;
        qb[off] = __float2bfloat16(sq);
        kb[off] = __float2bfloat16(sk);
        vb[off] = __float2bfloat16(sv);
    }
}

// ---------------- tiled transpose + cast to bf16 ----------------
// in: [z][R][Cc]  -> out: [z][Cc][R]
template <typename Tin>
__global__ __launch_bounds__(256) void transpose_cast(
    const Tin* __restrict__ in, __hip_bfloat16* __restrict__ out,
    int R, int Cc, long inz, long outz)
{
    __shared__ float tile[32][33];
    const long z = blockIdx.z;
    const int c0 = blockIdx.x * 32, r0 = blockIdx.y * 32;
    const int tx = threadIdx.x & 31, ty = threadIdx.x >> 5;   // 32 x 8
    const Tin* ip = in + z * inz;
    #pragma unroll
    for (int i = 0; i < 32; i += 8)
        tile[ty + i][tx] = tofloat(ip[(long)(r0 + ty + i) * Cc + (c0 + tx)]);
    __syncthreads();
    __hip_bfloat16* op = out + z * outz;
    #pragma unroll
    for (int i = 0; i < 32; i += 8)
        op[(long)(c0 + ty + i) * R + (r0 + tx)] = __float2bfloat16(tile[tx][ty + i]);
}

// ---------------- in-place row softmax over [rows][1024] bf16 ----------------
__global__ __launch_bounds__(256) void softmax_inplace(__hip_bfloat16* __restrict__ S)
{
    __shared__ float red[8];
    const long row = blockIdx.x;
    uint2* p = reinterpret_cast<uint2*>(S + row * 1024);
    const int tid = threadIdx.x;
    uint2 u = p[tid];
    float v0 = us2f(u.x & 0xffffu), v1 = us2f(u.x >> 16);
    float v2 = us2f(u.y & 0xffffu), v3 = us2f(u.y >> 16);

    float m = fmaxf(fmaxf(v0, v1), fmaxf(v2, v3));
    for (int o = 32; o; o >>= 1) m = fmaxf(m, __shfl_xor(m, o));
    const int wave = tid >> 6, lane = tid & 63;
    if (lane == 0) red[wave] = m;
    __syncthreads();
    m = fmaxf(fmaxf(red[0], red[1]), fmaxf(red[2], red[3]));

    float e0 = expf(v0 - m), e1 = expf(v1 - m), e2 = expf(v2 - m), e3 = expf(v3 - m);
    float s = e0 + e1 + e2 + e3;
    for (int o = 32; o; o >>= 1) s += __shfl_xor(s, o);
    if (lane == 0) red[4 + wave] = s;
    __syncthreads();
    s = red[4] + red[5] + red[6] + red[7];
    const float inv = 1.0f / s;

    u.x = (unsigned int)f2b_raw(e0 * inv) | ((unsigned int)f2b_raw(e1 * inv) << 16);
    u.y = (unsigned int)f2b_raw(e2 * inv) | ((unsigned int)f2b_raw(e3 * inv) << 16);
    p[tid] = u;
}

// ---------------- NT bf16 GEMM: C[M,N] = A[M,K] * B[N,K]^T ----------------
// 128x128 tile, BK=32, 4 waves (2x2), 16x16x32 MFMA, register-staged LDS.
// MODE 0: QK  (C *= SCALE)                  -> bf16 C
// MODE 1: reatten (affine per col j)        -> fp32 C (d_out) + bf16 C2 (ws)
// MODE 2: PV  (C offset from zg=z+zoff)     -> bf16 C
// MODE 3: proj (C += bias[col])             -> fp32 C (d_out)
template <int MODE>
__global__ __launch_bounds__(256) void gemm_nt(
    const __hip_bfloat16* __restrict__ Aall, const __hip_bfloat16* __restrict__ Ball,
    void* __restrict__ Call, __hip_bfloat16* __restrict__ C2all,
    int K, long strideAz, long strideBz, long strideCz, int zoff,
    const float* __restrict__ e0, const float* __restrict__ e1, const float* __restrict__ e2)
{
    __shared__ __align__(16) short As[128 * 32];
    __shared__ __align__(16) short Bs[128 * 32];

    const int tid = threadIdx.x;
    const int z = blockIdx.z;
    const int tileM = blockIdx.x, tileN = blockIdx.y;

    const short* Aw = (const short*)Aall + strideAz * z + (long)tileM * 128 * K;
    const short* Bw = (const short*)Ball + strideBz * z + (long)tileN * 128 * K;

    const int r0s = tid >> 2, k0s = (tid & 3) * 8;
    const int r1s = r0s + 64;

    f32x4 acc[4][4];
    #pragma unroll
    for (int m = 0; m < 4; ++m)
        #pragma unroll
        for (int n = 0; n < 4; ++n) acc[m][n] = (f32x4){0.f, 0.f, 0.f, 0.f};

    const int lane = tid & 63;
    const int wave = tid >> 6;
    const int wr = (wave >> 1) * 64, wc = (wave & 1) * 64;
    const int fr = lane & 15;
    const int kb = (lane >> 4) * 8;

    const int nk = K >> 5;
    for (int kt = 0; kt < nk; ++kt) {
        const short* Ak = Aw + kt * 32 + k0s;
        const short* Bk = Bw + kt * 32 + k0s;
        short8 a0 = *(const short8*)(Ak + (long)r0s * K);
        short8 a1 = *(const short8*)(Ak + (long)r1s * K);
        short8 b0 = *(const short8*)(Bk + (long)r0s * K);
        short8 b1 = *(const short8*)(Bk + (long)r1s * K);
        __syncthreads();                 // previous tile fully consumed
        *(short8*)&As[tid * 8] = a0;
        *(short8*)&As[(tid + 256) * 8] = a1;
        *(short8*)&Bs[tid * 8] = b0;
        *(short8*)&Bs[(tid + 256) * 8] = b1;
        __syncthreads();                 // staging visible

        short8 af[4], bf[4];
        #pragma unroll
        for (int m = 0; m < 4; ++m) af[m] = *(const short8*)&As[(wr + m * 16 + fr) * 32 + kb];
        #pragma unroll
        for (int n = 0; n < 4; ++n) bf[n] = *(const short8*)&Bs[(wc + n * 16 + fr) * 32 + kb];
        #pragma unroll
        for (int m = 0; m < 4; ++m)
            #pragma unroll
            for (int n = 0; n < 4; ++n)
                acc[m][n] = __builtin_amdgcn_mfma_f32_16x16x32_bf16(af[m], bf[n], acc[m][n], 0, 0, 0);
    }

    long base;
    if (MODE == 2) {
        const int zg = z + zoff;
        base = (long)(zg >> 3) * 1048576 + (long)(zg & 7) * 128;
    } else {
        base = strideCz * z;
    }

    #pragma unroll
    for (int n = 0; n < 4; ++n) {
        const int col = tileN * 128 + wc + n * 16 + fr;
        float alpha = 1.f, addv = 0.f;
        if (MODE == 0) alpha = 0.08838834764831843f;   // 128^-0.5
        if (MODE == 1) {
            const float g = e0[col], rbv = e1[col], bt = e2[col];
            alpha = g * rsqrtf(1.0f + 1e-3f);
            addv = rbv * alpha + bt;
        }
        if (MODE == 3) addv = e0[col];
        #pragma unroll
        for (int m = 0; m < 4; ++m) {
            const int row0 = tileM * 128 + wr + m * 16 + (lane >> 4) * 4;
            #pragma unroll
            for (int r = 0; r < 4; ++r) {
                const float v = acc[m][n][r] * alpha + addv;
                const long off = base + (long)(row0 + r) * 1024 + col;
                if (MODE == 1) {
                    ((float*)Call)[off] = v;
                    C2all[off] = __float2bfloat16(v);
                } else if (MODE == 3) {
                    ((float*)Call)[off] = v;
                } else {
                    ((__hip_bfloat16*)Call)[off] = __float2bfloat16(v);
                }
            }
        }
    }
}

extern "C" void kernel_launch(void* const* d_in, const int* in_sizes, int n_in,
                              void* d_out, int out_size, void* d_ws, size_t ws_size,
                              hipStream_t stream)
{
    const float* x  = (const float*)d_in[0];
    const float* qw = (const float*)d_in[1];
    const float* kw = (const float*)d_in[2];
    const float* vw = (const float*)d_in[3];
    const float* rw = (const float*)d_in[4];
    const float* rb = (const float*)d_in[5];
    const float* bg = (const float*)d_in[6];
    const float* bb = (const float*)d_in[7];
    const float* pw = (const float*)d_in[8];
    const float* pb = (const float*)d_in[9];

    float* outF  = (float*)d_out;          // [8,1024,1024] fp32
    float* attnF = outF + 8388608;         // [8,8,1024,1024] fp32

    // workspace (~121 MiB)
    char* w = (char*)d_ws;
    __hip_bfloat16* qb    = (__hip_bfloat16*)w; w += 16777216;   // [64,1024,128]
    __hip_bfloat16* kb    = (__hip_bfloat16*)w; w += 16777216;
    __hip_bfloat16* vb    = (__hip_bfloat16*)w; w += 16777216;
    __hip_bfloat16* vt    = (__hip_bfloat16*)w; w += 16777216;   // [64,128,1024]
    __hip_bfloat16* Wt    = (__hip_bfloat16*)w; w += 2097152;    // [1024,1024] reatten_w^T
    __hip_bfloat16* pWt   = (__hip_bfloat16*)w; w += 2097152;    // [1024,1024] proj_w^T
    __hip_bfloat16* o2    = (__hip_bfloat16*)w; w += 16777216;   // [8192,1024]
    __hip_bfloat16* Sq    = (__hip_bfloat16*)w; w += 16777216;   // [8,1024,1024] eighth
    __hip_bfloat16* attnb = (__hip_bfloat16*)w; w += 16777216;   // [8,1024,1024] eighth (bf16 attn)

    conv_qkv<<<8192, 256, 0, stream>>>(x, qw, kw, vw, qb, kb, vb);
    transpose_cast<float><<<dim3(32, 32, 1), 256, 0, stream>>>(rw, Wt, 1024, 1024, 0, 0);
    transpose_cast<float><<<dim3(32, 32, 1), 256, 0, stream>>>(pw, pWt, 1024, 1024, 0, 0);
    transpose_cast<__hip_bfloat16><<<dim3(4, 32, 64), 256, 0, stream>>>(vb, vt, 1024, 128, 131072, 131072);

    for (int e = 0; e < 8; ++e) {
        const long zq = (long)e * 8;
        // S = q k^T * scale (eighth of heads), bf16
        gemm_nt<0><<<dim3(8, 8, 8), 256, 0, stream>>>(
            qb + zq * 131072, kb + zq * 131072, Sq, nullptr, 128,
            131072, 131072, 1048576, 0, nullptr, nullptr, nullptr);
        softmax_inplace<<<8192, 256, 0, stream>>>(Sq);
        // attn = (P @ W + rb)*gamma/sqrt(1+eps) + beta -> fp32 d_out + bf16 ws copy
        gemm_nt<1><<<dim3(8, 8, 8), 256, 0, stream>>>(
            Sq, Wt, attnF + zq * 1048576, attnb, 1024,
            1048576, 0, 1048576, 0, bg, rb, bb);
        // o2[b, i, h*128+d] = attn @ v
        gemm_nt<2><<<dim3(8, 1, 8), 256, 0, stream>>>(
            attnb, vt + zq * 131072, o2, nullptr, 1024,
            1048576, 131072, 0, (int)zq, nullptr, nullptr, nullptr);
    }
    // out = o2 @ proj_w + proj_b  (fp32)
    gemm_nt<3><<<dim3(64, 8, 1), 256, 0, stream>>>(
        o2, pWt, outF, nullptr, 1024, 0, 0, 0, 0, pb, nullptr, nullptr);
}

// Round 4
// 546.503 us; speedup vs baseline: 1.3485x; 1.3485x over previous
//
#include <hip/hip_runtime.h>
#include <hip/hip_bf16.h>

typedef __attribute__((ext_vector_type(8))) short short8;
typedef __attribute__((ext_vector_type(4))) float f32x4;

__device__ __forceinline__ void gload_lds16(const void* g, void* l) {
    __builtin_amdgcn_global_load_lds(
        (const __attribute__((address_space(1))) void*)g,
        (__attribute__((address_space(3))) void*)l, 16, 0, 0);
}

__device__ __forceinline__ float gelu_exact(float x) {
    return 0.5f * x * (1.0f + erff(x * 0.70710678118654752f));
}
__device__ __forceinline__ float us2f(unsigned int u) {
    return __uint_as_float(u << 16);
}
__device__ __forceinline__ unsigned short f2b_raw(float f) {
    __hip_bfloat16 h = __float2bfloat16(f);
    return *reinterpret_cast<unsigned short*>(&h);
}
__device__ __forceinline__ float tofloat(float f) { return f; }
__device__ __forceinline__ float tofloat(__hip_bfloat16 h) { return __bfloat162float(h); }

// ---------------- conv 3x3 (C=1) + exact GELU over 32x32 patches ----------------
__global__ __launch_bounds__(256) void conv_qkv(
    const float* __restrict__ x,
    const float* __restrict__ qw, const float* __restrict__ kw, const float* __restrict__ vw,
    __hip_bfloat16* __restrict__ qb, __hip_bfloat16* __restrict__ kb, __hip_bfloat16* __restrict__ vb)
{
    __shared__ float img[1024];
    const int bid = blockIdx.x;            // b*1024 + n
    const int b = bid >> 10, n = bid & 1023;
    const float* xr = x + (long)bid * 1024;
    for (int i = threadIdx.x; i < 1024; i += 256) img[i] = xr[i];
    __syncthreads();

    float wq[9], wk[9], wv[9];
    #pragma unroll
    for (int i = 0; i < 9; ++i) { wq[i] = qw[i]; wk[i] = kw[i]; wv[i] = vw[i]; }

    for (int q = 0; q < 4; ++q) {
        const int p = q * 256 + threadIdx.x;    // 0..1023 spatial
        const int r = p >> 5, c = p & 31;
        float sq = 0.f, sk = 0.f, sv = 0.f;
        #pragma unroll
        for (int dy = 0; dy < 3; ++dy) {
            const int rr = r + dy - 1;
            if (rr < 0 || rr > 31) continue;
            #pragma unroll
            for (int dx = 0; dx < 3; ++dx) {
                const int cc = c + dx - 1;
                if (cc < 0 || cc > 31) continue;
                const float px = img[rr * 32 + cc];
                sq += px * wq[dy * 3 + dx];
                sk += px * wk[dy * 3 + dx];
                sv += px * wv[dy * 3 + dx];
            }
        }
        sq = gelu_exact(sq); sk = gelu_exact(sk); sv = gelu_exact(sv);
        const int h = p >> 7, d = p & 127;
        const long off = ((long)(b * 8 + h) * 1024 + n) * 128 + d;
        qb[off] = __float2bfloat16(sq);
        kb[off] = __float2bfloat16(sk);
        vb[off] = __float2bfloat16(sv);
    }
}

// ---------------- tiled transpose + cast to bf16 ----------------
template <typename Tin>
__global__ __launch_bounds__(256) void transpose_cast(
    const Tin* __restrict__ in, __hip_bfloat16* __restrict__ out,
    int R, int Cc, long inz, long outz)
{
    __shared__ float tile[32][33];
    const long z = blockIdx.z;
    const int c0 = blockIdx.x * 32, r0 = blockIdx.y * 32;
    const int tx = threadIdx.x & 31, ty = threadIdx.x >> 5;   // 32 x 8
    const Tin* ip = in + z * inz;
    #pragma unroll
    for (int i = 0; i < 32; i += 8)
        tile[ty + i][tx] = tofloat(ip[(long)(r0 + ty + i) * Cc + (c0 + tx)]);
    __syncthreads();
    __hip_bfloat16* op = out + z * outz;
    #pragma unroll
    for (int i = 0; i < 32; i += 8)
        op[(long)(c0 + ty + i) * R + (r0 + tx)] = __float2bfloat16(tile[tx][ty + i]);
}

// ---------------- in-place row softmax over [rows][1024] bf16 ----------------
__global__ __launch_bounds__(256) void softmax_inplace(__hip_bfloat16* __restrict__ S)
{
    __shared__ float red[8];
    const long row = blockIdx.x;
    uint2* p = reinterpret_cast<uint2*>(S + row * 1024);
    const int tid = threadIdx.x;
    uint2 u = p[tid];
    float v0 = us2f(u.x & 0xffffu), v1 = us2f(u.x >> 16);
    float v2 = us2f(u.y & 0xffffu), v3 = us2f(u.y >> 16);

    float m = fmaxf(fmaxf(v0, v1), fmaxf(v2, v3));
    for (int o = 32; o; o >>= 1) m = fmaxf(m, __shfl_xor(m, o));
    const int wave = tid >> 6, lane = tid & 63;
    if (lane == 0) red[wave] = m;
    __syncthreads();
    m = fmaxf(fmaxf(red[0], red[1]), fmaxf(red[2], red[3]));

    float e0 = expf(v0 - m), e1 = expf(v1 - m), e2 = expf(v2 - m), e3 = expf(v3 - m);
    float s = e0 + e1 + e2 + e3;
    for (int o = 32; o; o >>= 1) s += __shfl_xor(s, o);
    if (lane == 0) red[4 + wave] = s;
    __syncthreads();
    s = red[4] + red[5] + red[6] + red[7];
    const float inv = 1.0f / s;

    u.x = (unsigned int)f2b_raw(e0 * inv) | ((unsigned int)f2b_raw(e1 * inv) << 16);
    u.y = (unsigned int)f2b_raw(e2 * inv) | ((unsigned int)f2b_raw(e3 * inv) << 16);
    p[tid] = u;
}

// ---------------- NT bf16 GEMM: C[M,N] = A[M,K] * B[N,K]^T ----------------
// 128x128 tile, BK=32, 4 waves (2x2), 16x16x32 MFMA, global_load_lds staging (m97).
// MODE 0: QK  (C *= SCALE)                  -> bf16 C
// MODE 1: reatten (affine per col j)        -> fp32 C (d_out) + bf16 C2 (ws)
// MODE 2: PV  (C offset from z)             -> bf16 C
// MODE 3: proj (C += bias[col])             -> fp32 C (d_out)
template <int MODE>
__global__ __launch_bounds__(256) void gemm_nt(
    const __hip_bfloat16* __restrict__ Aall, const __hip_bfloat16* __restrict__ Ball,
    void* __restrict__ Call, __hip_bfloat16* __restrict__ C2all,
    int K, long strideAz, long strideBz, long strideCz,
    const float* __restrict__ e0, const float* __restrict__ e1, const float* __restrict__ e2)
{
    __shared__ __align__(16) short As[128 * 32];
    __shared__ __align__(16) short Bs[128 * 32];

    const int tid = threadIdx.x;
    const int z = blockIdx.z;
    const int tileM = blockIdx.x, tileN = blockIdx.y;

    const short* Aw = (const short*)Aall + strideAz * z + (long)tileM * 128 * K;
    const short* Bw = (const short*)Ball + strideBz * z + (long)tileN * 128 * K;

    const int r0s = tid >> 2, k0s = (tid & 3) * 8;   // rows 0..63, k-chunk
    const int r1s = r0s + 64;                         // rows 64..127

    f32x4 acc[4][4];
    #pragma unroll
    for (int m = 0; m < 4; ++m)
        #pragma unroll
        for (int n = 0; n < 4; ++n) acc[m][n] = (f32x4){0.f, 0.f, 0.f, 0.f};

    const int lane = tid & 63;
    const int wave = tid >> 6;
    const int wr = (wave >> 1) * 64, wc = (wave & 1) * 64;
    const int fr = lane & 15;
    const int kb = (lane >> 4) * 8;

    const int nk = K >> 5;
    for (int kt = 0; kt < nk; ++kt) {
        __syncthreads();                 // previous tile fully consumed
        gload_lds16(Aw + (long)r0s * K + kt * 32 + k0s, &As[tid * 8]);
        gload_lds16(Aw + (long)r1s * K + kt * 32 + k0s, &As[(tid + 256) * 8]);
        gload_lds16(Bw + (long)r0s * K + kt * 32 + k0s, &Bs[tid * 8]);
        gload_lds16(Bw + (long)r1s * K + kt * 32 + k0s, &Bs[(tid + 256) * 8]);
        __syncthreads();                 // drains vmcnt -> staging visible

        short8 af[4], bf[4];
        #pragma unroll
        for (int m = 0; m < 4; ++m) af[m] = *(const short8*)&As[(wr + m * 16 + fr) * 32 + kb];
        #pragma unroll
        for (int n = 0; n < 4; ++n) bf[n] = *(const short8*)&Bs[(wc + n * 16 + fr) * 32 + kb];
        #pragma unroll
        for (int m = 0; m < 4; ++m)
            #pragma unroll
            for (int n = 0; n < 4; ++n)
                acc[m][n] = __builtin_amdgcn_mfma_f32_16x16x32_bf16(af[m], bf[n], acc[m][n], 0, 0, 0);
    }

    long base;
    if (MODE == 2) base = (long)(z >> 3) * 1048576 + (long)(z & 7) * 128;
    else           base = strideCz * z;

    #pragma unroll
    for (int n = 0; n < 4; ++n) {
        const int col = tileN * 128 + wc + n * 16 + fr;
        float alpha = 1.f, addv = 0.f;
        if (MODE == 0) alpha = 0.08838834764831843f;   // 128^-0.5
        if (MODE == 1) {
            const float g = e0[col], rbv = e1[col], bt = e2[col];
            alpha = g * rsqrtf(1.0f + 1e-3f);
            addv = rbv * alpha + bt;
        }
        if (MODE == 3) addv = e0[col];
        #pragma unroll
        for (int m = 0; m < 4; ++m) {
            const int row0 = tileM * 128 + wr + m * 16 + (lane >> 4) * 4;
            #pragma unroll
            for (int r = 0; r < 4; ++r) {
                const float v = acc[m][n][r] * alpha + addv;
                const long off = base + (long)(row0 + r) * 1024 + col;
                if (MODE == 1) {
                    ((float*)Call)[off] = v;
                    C2all[off] = __float2bfloat16(v);
                } else if (MODE == 3) {
                    ((float*)Call)[off] = v;
                } else {
                    ((__hip_bfloat16*)Call)[off] = __float2bfloat16(v);
                }
            }
        }
    }
}

extern "C" void kernel_launch(void* const* d_in, const int* in_sizes, int n_in,
                              void* d_out, int out_size, void* d_ws, size_t ws_size,
                              hipStream_t stream)
{
    const float* x  = (const float*)d_in[0];
    const float* qw = (const float*)d_in[1];
    const float* kw = (const float*)d_in[2];
    const float* vw = (const float*)d_in[3];
    const float* rw = (const float*)d_in[4];
    const float* rb = (const float*)d_in[5];
    const float* bg = (const float*)d_in[6];
    const float* bb = (const float*)d_in[7];
    const float* pw = (const float*)d_in[8];
    const float* pb = (const float*)d_in[9];

    float* outF  = (float*)d_out;          // [8,1024,1024] fp32
    float* attnF = outF + 8388608;         // [8,8,1024,1024] fp32

    // workspace (~390 MiB of ~1.15 GiB)
    char* w = (char*)d_ws;
    __hip_bfloat16* qb    = (__hip_bfloat16*)w; w += 16777216;    // [64,1024,128]
    __hip_bfloat16* kb    = (__hip_bfloat16*)w; w += 16777216;
    __hip_bfloat16* vb    = (__hip_bfloat16*)w; w += 16777216;
    __hip_bfloat16* vt    = (__hip_bfloat16*)w; w += 16777216;    // [64,128,1024]
    __hip_bfloat16* Wt    = (__hip_bfloat16*)w; w += 2097152;     // [1024,1024] reatten_w^T
    __hip_bfloat16* pWt   = (__hip_bfloat16*)w; w += 2097152;     // [1024,1024] proj_w^T
    __hip_bfloat16* o2    = (__hip_bfloat16*)w; w += 16777216;    // [8192,1024]
    __hip_bfloat16* S     = (__hip_bfloat16*)w; w += 134217728;   // [64,1024,1024]
    __hip_bfloat16* attnb = (__hip_bfloat16*)w; w += 134217728;   // [64,1024,1024]

    conv_qkv<<<8192, 256, 0, stream>>>(x, qw, kw, vw, qb, kb, vb);
    transpose_cast<float><<<dim3(32, 32, 1), 256, 0, stream>>>(rw, Wt, 1024, 1024, 0, 0);
    transpose_cast<float><<<dim3(32, 32, 1), 256, 0, stream>>>(pw, pWt, 1024, 1024, 0, 0);
    transpose_cast<__hip_bfloat16><<<dim3(4, 32, 64), 256, 0, stream>>>(vb, vt, 1024, 128, 131072, 131072);

    // S = q k^T * scale  (all 64 heads)
    gemm_nt<0><<<dim3(8, 8, 64), 256, 0, stream>>>(
        qb, kb, S, nullptr, 128, 131072, 131072, 1048576, nullptr, nullptr, nullptr);
    // row softmax in place
    softmax_inplace<<<65536, 256, 0, stream>>>(S);
    // attn = (P @ W + rb)*gamma/sqrt(1+eps) + beta -> fp32 d_out + bf16 ws
    gemm_nt<1><<<dim3(8, 8, 64), 256, 0, stream>>>(
        S, Wt, attnF, attnb, 1024, 1048576, 0, 1048576, bg, rb, bb);
    // o2[b, i, h*128+d] = attn @ v
    gemm_nt<2><<<dim3(8, 1, 64), 256, 0, stream>>>(
        attnb, vt, o2, nullptr, 1024, 1048576, 131072, 0, nullptr, nullptr, nullptr);
    // out = o2 @ proj_w + proj_b  (fp32)
    gemm_nt<3><<<dim3(64, 8, 1), 256, 0, stream>>>(
        o2, pWt, outF, nullptr, 1024, 0, 0, 0, pb, nullptr, nullptr);
}

// Round 5
// 460.926 us; speedup vs baseline: 1.5989x; 1.1857x over previous
//
#include <hip/hip_runtime.h>
#include <hip/hip_bf16.h>

typedef __attribute__((ext_vector_type(8))) short short8;
typedef __attribute__((ext_vector_type(4))) float f32x4;

__device__ __forceinline__ void gload_lds16(const void* g, void* l) {
    __builtin_amdgcn_global_load_lds(
        (const __attribute__((address_space(1))) void*)g,
        (__attribute__((address_space(3))) void*)l, 16, 0, 0);
}

__device__ __forceinline__ float gelu_exact(float x) {
    return 0.5f * x * (1.0f + erff(x * 0.70710678118654752f));
}
__device__ __forceinline__ float us2f(unsigned int u) {
    return __uint_as_float(u << 16);
}
__device__ __forceinline__ unsigned short f2b_raw(float f) {
    __hip_bfloat16 h = __float2bfloat16(f);
    return *reinterpret_cast<unsigned short*>(&h);
}
__device__ __forceinline__ float tofloat(float f) { return f; }
__device__ __forceinline__ float tofloat(__hip_bfloat16 h) { return __bfloat162float(h); }

// ---------------- conv 3x3 (C=1) + exact GELU over 32x32 patches ----------------
__global__ __launch_bounds__(256) void conv_qkv(
    const float* __restrict__ x,
    const float* __restrict__ qw, const float* __restrict__ kw, const float* __restrict__ vw,
    __hip_bfloat16* __restrict__ qb, __hip_bfloat16* __restrict__ kb, __hip_bfloat16* __restrict__ vb)
{
    __shared__ float img[1024];
    const int bid = blockIdx.x;            // b*1024 + n
    const int b = bid >> 10, n = bid & 1023;
    const float* xr = x + (long)bid * 1024;
    for (int i = threadIdx.x; i < 1024; i += 256) img[i] = xr[i];
    __syncthreads();

    float wq[9], wk[9], wv[9];
    #pragma unroll
    for (int i = 0; i < 9; ++i) { wq[i] = qw[i]; wk[i] = kw[i]; wv[i] = vw[i]; }

    for (int q = 0; q < 4; ++q) {
        const int p = q * 256 + threadIdx.x;    // 0..1023 spatial
        const int r = p >> 5, c = p & 31;
        float sq = 0.f, sk = 0.f, sv = 0.f;
        #pragma unroll
        for (int dy = 0; dy < 3; ++dy) {
            const int rr = r + dy - 1;
            if (rr < 0 || rr > 31) continue;
            #pragma unroll
            for (int dx = 0; dx < 3; ++dx) {
                const int cc = c + dx - 1;
                if (cc < 0 || cc > 31) continue;
                const float px = img[rr * 32 + cc];
                sq += px * wq[dy * 3 + dx];
                sk += px * wk[dy * 3 + dx];
                sv += px * wv[dy * 3 + dx];
            }
        }
        sq = gelu_exact(sq); sk = gelu_exact(sk); sv = gelu_exact(sv);
        const int h = p >> 7, d = p & 127;
        const long off = ((long)(b * 8 + h) * 1024 + n) * 128 + d;
        qb[off] = __float2bfloat16(sq);
        kb[off] = __float2bfloat16(sk);
        vb[off] = __float2bfloat16(sv);
    }
}

// ---------------- tiled transpose + cast to bf16 ----------------
template <typename Tin>
__global__ __launch_bounds__(256) void transpose_cast(
    const Tin* __restrict__ in, __hip_bfloat16* __restrict__ out,
    int R, int Cc, long inz, long outz)
{
    __shared__ float tile[32][33];
    const long z = blockIdx.z;
    const int c0 = blockIdx.x * 32, r0 = blockIdx.y * 32;
    const int tx = threadIdx.x & 31, ty = threadIdx.x >> 5;   // 32 x 8
    const Tin* ip = in + z * inz;
    #pragma unroll
    for (int i = 0; i < 32; i += 8)
        tile[ty + i][tx] = tofloat(ip[(long)(r0 + ty + i) * Cc + (c0 + tx)]);
    __syncthreads();
    __hip_bfloat16* op = out + z * outz;
    #pragma unroll
    for (int i = 0; i < 32; i += 8)
        op[(long)(c0 + ty + i) * R + (r0 + tx)] = __float2bfloat16(tile[tx][ty + i]);
}

// ---------------- in-place row softmax over [rows][1024] bf16 ----------------
__global__ __launch_bounds__(256) void softmax_inplace(__hip_bfloat16* __restrict__ S)
{
    __shared__ float red[8];
    const long row = blockIdx.x;
    uint2* p = reinterpret_cast<uint2*>(S + row * 1024);
    const int tid = threadIdx.x;
    uint2 u = p[tid];
    float v0 = us2f(u.x & 0xffffu), v1 = us2f(u.x >> 16);
    float v2 = us2f(u.y & 0xffffu), v3 = us2f(u.y >> 16);

    float m = fmaxf(fmaxf(v0, v1), fmaxf(v2, v3));
    for (int o = 32; o; o >>= 1) m = fmaxf(m, __shfl_xor(m, o));
    const int wave = tid >> 6, lane = tid & 63;
    if (lane == 0) red[wave] = m;
    __syncthreads();
    m = fmaxf(fmaxf(red[0], red[1]), fmaxf(red[2], red[3]));

    float e0 = expf(v0 - m), e1 = expf(v1 - m), e2 = expf(v2 - m), e3 = expf(v3 - m);
    float s = e0 + e1 + e2 + e3;
    for (int o = 32; o; o >>= 1) s += __shfl_xor(s, o);
    if (lane == 0) red[4 + wave] = s;
    __syncthreads();
    s = red[4] + red[5] + red[6] + red[7];
    const float inv = 1.0f / s;

    u.x = (unsigned int)f2b_raw(e0 * inv) | ((unsigned int)f2b_raw(e1 * inv) << 16);
    u.y = (unsigned int)f2b_raw(e2 * inv) | ((unsigned int)f2b_raw(e3 * inv) << 16);
    p[tid] = u;
}

// ---------------- NT bf16 GEMM: C[M,N] = A[M,K] * B[N,K]^T ----------------
// 128x128 tile, BK=32, 4 waves (2x2), 16x16x32 MFMA, global_load_lds staging.
// Coalesced LDS-bounce epilogue (32-row chunks).
// MODE 0: QK  (C *= SCALE)           -> bf16 C
// MODE 1: reatten (affine per col j) -> fp32 C (d_out attn)
// MODE 2: PV  (A is fp32! reg-staged + cvt; C offset from z) -> bf16 C
// MODE 3: proj (C += bias[col])      -> fp32 C (d_out)
template <int MODE>
__global__ __launch_bounds__(256) void gemm_nt(
    const void* __restrict__ Aall, const __hip_bfloat16* __restrict__ Ball,
    void* __restrict__ Call, int K,
    long sAz, long sBz, long sCz,
    const float* __restrict__ e0, const float* __restrict__ e1, const float* __restrict__ e2)
{
    constexpr bool AF32 = (MODE == 2);
    constexpr bool OF32 = (MODE == 1 || MODE == 3);

    __shared__ __align__(16) char smem[32 * 132 * 4];   // 16.9 KiB union
    short* As = (short*)smem;            // [128*32] bf16
    short* Bs = (short*)(smem + 8192);   // [128*32] bf16
    float* cbuf = (float*)smem;          // [32][132] fp32 epilogue bounce

    const int tid = threadIdx.x;
    const int z = blockIdx.z;
    const int tileM = blockIdx.x, tileN = blockIdx.y;

    const short* AwB = nullptr;
    const float* AwF = nullptr;
    if constexpr (AF32) AwF = (const float*)Aall + sAz * z + (long)tileM * 128 * K;
    else                AwB = (const short*)Aall + sAz * z + (long)tileM * 128 * K;
    const short* Bw = (const short*)Ball + sBz * z + (long)tileN * 128 * K;

    const int r0s = tid >> 2, k0s = (tid & 3) * 8;   // staging row / k-chunk
    const int r1s = r0s + 64;

    f32x4 acc[4][4];
    #pragma unroll
    for (int m = 0; m < 4; ++m)
        #pragma unroll
        for (int n = 0; n < 4; ++n) acc[m][n] = (f32x4){0.f, 0.f, 0.f, 0.f};

    const int lane = tid & 63;
    const int wave = tid >> 6;
    const int wr = (wave >> 1) * 64, wc = (wave & 1) * 64;
    const int fr = lane & 15;
    const int kb = (lane >> 4) * 8;

    const int nk = K >> 5;
    for (int kt = 0; kt < nk; ++kt) {
        if constexpr (AF32) {
            // register-staged fp32 -> bf16 (issue loads early, write after barrier)
            const float* Ak0 = AwF + (long)r0s * K + kt * 32 + k0s;
            const float* Ak1 = AwF + (long)r1s * K + kt * 32 + k0s;
            f32x4 a00 = *(const f32x4*)Ak0;
            f32x4 a01 = *(const f32x4*)(Ak0 + 4);
            f32x4 a10 = *(const f32x4*)Ak1;
            f32x4 a11 = *(const f32x4*)(Ak1 + 4);
            __syncthreads();                 // previous tile consumed
            short8 s0, s1;
            #pragma unroll
            for (int i = 0; i < 4; ++i) {
                s0[i] = (short)f2b_raw(a00[i]); s0[i + 4] = (short)f2b_raw(a01[i]);
                s1[i] = (short)f2b_raw(a10[i]); s1[i + 4] = (short)f2b_raw(a11[i]);
            }
            *(short8*)&As[tid * 8] = s0;
            *(short8*)&As[(tid + 256) * 8] = s1;
            gload_lds16(Bw + (long)r0s * K + kt * 32 + k0s, &Bs[tid * 8]);
            gload_lds16(Bw + (long)r1s * K + kt * 32 + k0s, &Bs[(tid + 256) * 8]);
            __syncthreads();                 // staging visible
        } else {
            __syncthreads();                 // previous tile consumed
            gload_lds16(AwB + (long)r0s * K + kt * 32 + k0s, &As[tid * 8]);
            gload_lds16(AwB + (long)r1s * K + kt * 32 + k0s, &As[(tid + 256) * 8]);
            gload_lds16(Bw + (long)r0s * K + kt * 32 + k0s, &Bs[tid * 8]);
            gload_lds16(Bw + (long)r1s * K + kt * 32 + k0s, &Bs[(tid + 256) * 8]);
            __syncthreads();                 // staging visible
        }

        short8 af[4], bf[4];
        #pragma unroll
        for (int m = 0; m < 4; ++m) af[m] = *(const short8*)&As[(wr + m * 16 + fr) * 32 + kb];
        #pragma unroll
        for (int n = 0; n < 4; ++n) bf[n] = *(const short8*)&Bs[(wc + n * 16 + fr) * 32 + kb];
        #pragma unroll
        for (int m = 0; m < 4; ++m)
            #pragma unroll
            for (int n = 0; n < 4; ++n)
                acc[m][n] = __builtin_amdgcn_mfma_f32_16x16x32_bf16(af[m], bf[n], acc[m][n], 0, 0, 0);
    }

    // ---- epilogue: affine + LDS bounce + coalesced wide stores ----
    long cbase;
    if (MODE == 2) cbase = (long)(z >> 3) * 1048576 + (long)(z & 7) * 128;
    else           cbase = sCz * z;

    float alpha[4], addv[4];
    #pragma unroll
    for (int n = 0; n < 4; ++n) {
        const int col = tileN * 128 + wc + n * 16 + fr;
        float a_ = 1.f, b_ = 0.f;
        if (MODE == 0) a_ = 0.08838834764831843f;     // 128^-0.5
        if (MODE == 1) {
            const float g = e0[col], rbv = e1[col], bt = e2[col];
            a_ = g * rsqrtf(1.0f + 1e-3f);
            b_ = rbv * a_ + bt;
        }
        if (MODE == 3) b_ = e0[col];
        alpha[n] = a_; addv[n] = b_;
    }

    __syncthreads();   // all LDS fragment reads done before cbuf overwrite
    #pragma unroll
    for (int q = 0; q < 4; ++q) {
        // fill chunk rows [32q, 32q+32) by the two waves owning that row range
        if ((wave >> 1) == (q >> 1)) {
            #pragma unroll
            for (int mm = 0; mm < 2; ++mm) {
                const int m = (q & 1) * 2 + mm;
                const int lr0 = m * 16 + (lane >> 4) * 4 - (q & 1) * 32;
                #pragma unroll
                for (int n = 0; n < 4; ++n)
                    #pragma unroll
                    for (int r = 0; r < 4; ++r)
                        cbuf[(lr0 + r) * 132 + wc + n * 16 + fr] = acc[m][n][r] * alpha[n] + addv[n];
            }
        }
        __syncthreads();
        const long growbase = (long)tileM * 128 + q * 32;
        if constexpr (OF32) {
            float* Cg = (float*)Call + cbase;
            #pragma unroll
            for (int pass = 0; pass < 4; ++pass) {
                const int idx = (tid + pass * 256) * 4;
                const int row = idx >> 7, col = idx & 127;
                f32x4 v = *(const f32x4*)&cbuf[row * 132 + col];
                *(f32x4*)&Cg[(growbase + row) * 1024 + tileN * 128 + col] = v;
            }
        } else {
            __hip_bfloat16* Cg = (__hip_bfloat16*)Call + cbase;
            #pragma unroll
            for (int pass = 0; pass < 2; ++pass) {
                const int idx = (tid + pass * 256) * 8;
                const int row = idx >> 7, col = idx & 127;
                const float* src = &cbuf[row * 132 + col];
                f32x4 v0 = *(const f32x4*)src;
                f32x4 v1 = *(const f32x4*)(src + 4);
                short8 s;
                #pragma unroll
                for (int i = 0; i < 4; ++i) {
                    s[i] = (short)f2b_raw(v0[i]);
                    s[i + 4] = (short)f2b_raw(v1[i]);
                }
                *(short8*)&Cg[(growbase + row) * 1024 + tileN * 128 + col] = s;
            }
        }
        __syncthreads();
    }
}

extern "C" void kernel_launch(void* const* d_in, const int* in_sizes, int n_in,
                              void* d_out, int out_size, void* d_ws, size_t ws_size,
                              hipStream_t stream)
{
    const float* x  = (const float*)d_in[0];
    const float* qw = (const float*)d_in[1];
    const float* kw = (const float*)d_in[2];
    const float* vw = (const float*)d_in[3];
    const float* rw = (const float*)d_in[4];
    const float* rb = (const float*)d_in[5];
    const float* bg = (const float*)d_in[6];
    const float* bb = (const float*)d_in[7];
    const float* pw = (const float*)d_in[8];
    const float* pb = (const float*)d_in[9];

    float* outF  = (float*)d_out;          // [8,1024,1024] fp32
    float* attnF = outF + 8388608;         // [8,8,1024,1024] fp32

    // workspace (~222 MiB of ~1.15 GiB)
    char* w = (char*)d_ws;
    __hip_bfloat16* qb    = (__hip_bfloat16*)w; w += 16777216;    // [64,1024,128]
    __hip_bfloat16* kb    = (__hip_bfloat16*)w; w += 16777216;
    __hip_bfloat16* vb    = (__hip_bfloat16*)w; w += 16777216;
    __hip_bfloat16* vt    = (__hip_bfloat16*)w; w += 16777216;    // [64,128,1024]
    __hip_bfloat16* Wt    = (__hip_bfloat16*)w; w += 2097152;     // [1024,1024] reatten_w^T
    __hip_bfloat16* pWt   = (__hip_bfloat16*)w; w += 2097152;     // [1024,1024] proj_w^T
    __hip_bfloat16* o2    = (__hip_bfloat16*)w; w += 16777216;    // [8192,1024]
    __hip_bfloat16* S     = (__hip_bfloat16*)w; w += 134217728;   // [64,1024,1024]

    conv_qkv<<<8192, 256, 0, stream>>>(x, qw, kw, vw, qb, kb, vb);
    transpose_cast<float><<<dim3(32, 32, 1), 256, 0, stream>>>(rw, Wt, 1024, 1024, 0, 0);
    transpose_cast<float><<<dim3(32, 32, 1), 256, 0, stream>>>(pw, pWt, 1024, 1024, 0, 0);
    transpose_cast<__hip_bfloat16><<<dim3(4, 32, 64), 256, 0, stream>>>(vb, vt, 1024, 128, 131072, 131072);

    // S = q k^T * scale  (all 64 heads), bf16
    gemm_nt<0><<<dim3(8, 8, 64), 256, 0, stream>>>(
        qb, kb, S, 128, 131072, 131072, 1048576, nullptr, nullptr, nullptr);
    // row softmax in place
    softmax_inplace<<<65536, 256, 0, stream>>>(S);
    // attn = (P @ W + rb)*gamma/sqrt(1+eps) + beta -> fp32 d_out only
    gemm_nt<1><<<dim3(8, 8, 64), 256, 0, stream>>>(
        S, Wt, attnF, 1024, 1048576, 0, 1048576, bg, rb, bb);
    // o2[b, i, h*128+d] = attn @ v   (A = fp32 attn, reg-staged cvt)
    gemm_nt<2><<<dim3(8, 1, 64), 256, 0, stream>>>(
        attnF, vt, o2, 1024, 1048576, 131072, 0, nullptr, nullptr, nullptr);
    // out = o2 @ proj_w + proj_b  (fp32)
    gemm_nt<3><<<dim3(64, 8, 1), 256, 0, stream>>>(
        o2, pWt, outF, 1024, 0, 0, 0, pb, nullptr, nullptr);
}

// Round 6
// 423.775 us; speedup vs baseline: 1.7391x; 1.0877x over previous
//
#include <hip/hip_runtime.h>
#include <hip/hip_bf16.h>

typedef __attribute__((ext_vector_type(8))) short short8;
typedef __attribute__((ext_vector_type(4))) float f32x4;

__device__ __forceinline__ void gload_lds16(const void* g, void* l) {
    __builtin_amdgcn_global_load_lds(
        (const __attribute__((address_space(1))) void*)g,
        (__attribute__((address_space(3))) void*)l, 16, 0, 0);
}

#define SBAR() do { __builtin_amdgcn_sched_barrier(0); __builtin_amdgcn_s_barrier(); __builtin_amdgcn_sched_barrier(0); } while (0)

__device__ __forceinline__ float gelu_exact(float x) {
    return 0.5f * x * (1.0f + erff(x * 0.70710678118654752f));
}
__device__ __forceinline__ float us2f(unsigned int u) {
    return __uint_as_float(u << 16);
}
__device__ __forceinline__ unsigned short f2b_raw(float f) {
    __hip_bfloat16 h = __float2bfloat16(f);
    return *reinterpret_cast<unsigned short*>(&h);
}
__device__ __forceinline__ float tofloat(float f) { return f; }
__device__ __forceinline__ float tofloat(__hip_bfloat16 h) { return __bfloat162float(h); }

// ---------------- conv 3x3 (C=1) + exact GELU over 32x32 patches ----------------
__global__ __launch_bounds__(256) void conv_qkv(
    const float* __restrict__ x,
    const float* __restrict__ qw, const float* __restrict__ kw, const float* __restrict__ vw,
    __hip_bfloat16* __restrict__ qb, __hip_bfloat16* __restrict__ kb, __hip_bfloat16* __restrict__ vb)
{
    __shared__ float img[1024];
    const int bid = blockIdx.x;            // b*1024 + n
    const int b = bid >> 10, n = bid & 1023;
    const float* xr = x + (long)bid * 1024;
    for (int i = threadIdx.x; i < 1024; i += 256) img[i] = xr[i];
    __syncthreads();

    float wq[9], wk[9], wv[9];
    #pragma unroll
    for (int i = 0; i < 9; ++i) { wq[i] = qw[i]; wk[i] = kw[i]; wv[i] = vw[i]; }

    for (int q = 0; q < 4; ++q) {
        const int p = q * 256 + threadIdx.x;    // 0..1023 spatial
        const int r = p >> 5, c = p & 31;
        float sq = 0.f, sk = 0.f, sv = 0.f;
        #pragma unroll
        for (int dy = 0; dy < 3; ++dy) {
            const int rr = r + dy - 1;
            if (rr < 0 || rr > 31) continue;
            #pragma unroll
            for (int dx = 0; dx < 3; ++dx) {
                const int cc = c + dx - 1;
                if (cc < 0 || cc > 31) continue;
                const float px = img[rr * 32 + cc];
                sq += px * wq[dy * 3 + dx];
                sk += px * wk[dy * 3 + dx];
                sv += px * wv[dy * 3 + dx];
            }
        }
        sq = gelu_exact(sq); sk = gelu_exact(sk); sv = gelu_exact(sv);
        const int h = p >> 7, d = p & 127;
        const long off = ((long)(b * 8 + h) * 1024 + n) * 128 + d;
        qb[off] = __float2bfloat16(sq);
        kb[off] = __float2bfloat16(sk);
        vb[off] = __float2bfloat16(sv);
    }
}

// ---------------- tiled transpose + cast to bf16 ----------------
template <typename Tin>
__global__ __launch_bounds__(256) void transpose_cast(
    const Tin* __restrict__ in, __hip_bfloat16* __restrict__ out,
    int R, int Cc, long inz, long outz)
{
    __shared__ float tile[32][33];
    const long z = blockIdx.z;
    const int c0 = blockIdx.x * 32, r0 = blockIdx.y * 32;
    const int tx = threadIdx.x & 31, ty = threadIdx.x >> 5;   // 32 x 8
    const Tin* ip = in + z * inz;
    #pragma unroll
    for (int i = 0; i < 32; i += 8)
        tile[ty + i][tx] = tofloat(ip[(long)(r0 + ty + i) * Cc + (c0 + tx)]);
    __syncthreads();
    __hip_bfloat16* op = out + z * outz;
    #pragma unroll
    for (int i = 0; i < 32; i += 8)
        op[(long)(c0 + ty + i) * R + (r0 + tx)] = __float2bfloat16(tile[tx][ty + i]);
}

// ---------------- in-place row softmax over [rows][1024] bf16 ----------------
__global__ __launch_bounds__(256) void softmax_inplace(__hip_bfloat16* __restrict__ S)
{
    __shared__ float red[8];
    const long row = blockIdx.x;
    uint2* p = reinterpret_cast<uint2*>(S + row * 1024);
    const int tid = threadIdx.x;
    uint2 u = p[tid];
    float v0 = us2f(u.x & 0xffffu), v1 = us2f(u.x >> 16);
    float v2 = us2f(u.y & 0xffffu), v3 = us2f(u.y >> 16);

    float m = fmaxf(fmaxf(v0, v1), fmaxf(v2, v3));
    for (int o = 32; o; o >>= 1) m = fmaxf(m, __shfl_xor(m, o));
    const int wave = tid >> 6, lane = tid & 63;
    if (lane == 0) red[wave] = m;
    __syncthreads();
    m = fmaxf(fmaxf(red[0], red[1]), fmaxf(red[2], red[3]));

    float e0 = expf(v0 - m), e1 = expf(v1 - m), e2 = expf(v2 - m), e3 = expf(v3 - m);
    float s = e0 + e1 + e2 + e3;
    for (int o = 32; o; o >>= 1) s += __shfl_xor(s, o);
    if (lane == 0) red[4 + wave] = s;
    __syncthreads();
    s = red[4] + red[5] + red[6] + red[7];
    const float inv = 1.0f / s;

    u.x = (unsigned int)f2b_raw(e0 * inv) | ((unsigned int)f2b_raw(e1 * inv) << 16);
    u.y = (unsigned int)f2b_raw(e2 * inv) | ((unsigned int)f2b_raw(e3 * inv) << 16);
    p[tid] = u;
}

// ---------------- reatten 256x256 8-phase-style GEMM ----------------
// C[z][1024][1024] fp32 = softmax(S)[z] @ Wt^T (NT), affine per out-col.
// 512 thr = 8 waves (2M x 4N), BK=32, 4 LDS K-tile buffers, stage t+2 while
// computing t, counted vmcnt(4) at K-tile boundaries, XOR-swizzled LDS.
__global__ __launch_bounds__(512, 2) void gemm_reatten_256(
    const __hip_bfloat16* __restrict__ Sall, const __hip_bfloat16* __restrict__ Wt,
    float* __restrict__ Cout,
    const float* __restrict__ bg, const float* __restrict__ rb, const float* __restrict__ bb)
{
    __shared__ __align__(16) char smem[131072];
    char* ldsA = smem;            // 4 x 16384 (A: [256 rows][32 k] bf16, swizzled)
    char* ldsB = smem + 65536;    // 4 x 16384

    const int tid = threadIdx.x;
    const int z = blockIdx.z, tileM = blockIdx.x, tileN = blockIdx.y;
    const char* Ab = (const char*)(Sall + (long)z * 1048576 + (long)tileM * 256 * 1024);
    const char* Bb = (const char*)(Wt + (long)tileN * 256 * 1024);

    // staging map: thread writes 2 linear 16B chunks; global src is inverse-swizzled
    int grow[2], goff[2], pphys[2];
    #pragma unroll
    for (int i = 0; i < 2; ++i) {
        const int p = i * 8192 + tid * 16;
        const int l = p ^ (((p >> 7) & 3) << 4);   // involution
        pphys[i] = p; grow[i] = l >> 6; goff[i] = l & 63;
    }
    auto STAGE = [&](const char* gb, char* lb, int kt) {
        #pragma unroll
        for (int i = 0; i < 2; ++i)
            gload_lds16(gb + (long)grow[i] * 2048 + kt * 64 + goff[i], lb + pphys[i]);
    };

    const int lane = tid & 63, wid = tid >> 6;
    const int wrM = wid >> 2, wcn = wid & 3;        // 2 x 4 wave grid
    const int fr = lane & 15, kl = lane >> 4;
    const int frbase = fr * 64 + kl * 16;           // logical byte of (row=fr, k=kl*8)

    auto LD8 = [&](const char* buf, int L) -> short8 {
        const int ph = L ^ (((L >> 7) & 3) << 4);   // swizzled read
        return *(const short8*)(buf + ph);
    };

    f32x4 acc[8][4];
    #pragma unroll
    for (int m = 0; m < 8; ++m)
        #pragma unroll
        for (int n = 0; n < 4; ++n) acc[m][n] = (f32x4){0.f, 0.f, 0.f, 0.f};

    // prologue: stage K-tiles 0,1
    STAGE(Ab, ldsA, 0);          STAGE(Bb, ldsB, 0);
    STAGE(Ab, ldsA + 16384, 1);  STAGE(Bb, ldsB + 16384, 1);
    asm volatile("s_waitcnt vmcnt(4)" ::: "memory");   // K-tile 0 landed
    SBAR();

    #pragma unroll 1
    for (int t = 0; t < 32; ++t) {
        char* bufA = ldsA + (t & 3) * 16384;
        char* bufB = ldsB + (t & 3) * 16384;
        const int t2 = t + 2;
        char* nA = ldsA + (t2 & 3) * 16384;
        char* nB = ldsB + (t2 & 3) * 16384;

        // ---- phase A: ds-read B frags + A half0; stage A(t+2); 16 MFMA
        short8 bf[4], af[4];
        #pragma unroll
        for (int n = 0; n < 4; ++n) bf[n] = LD8(bufB, ((wcn * 64 + n * 16) * 64) + frbase);
        #pragma unroll
        for (int j = 0; j < 4; ++j) af[j] = LD8(bufA, ((wrM * 128 + j * 16) * 64) + frbase);
        if (t2 < 32) STAGE(Ab, nA, t2);
        SBAR();
        asm volatile("s_waitcnt lgkmcnt(0)" ::: "memory");
        __builtin_amdgcn_sched_barrier(0);
        __builtin_amdgcn_s_setprio(1);
        #pragma unroll
        for (int j = 0; j < 4; ++j)
            #pragma unroll
            for (int n = 0; n < 4; ++n)
                acc[j][n] = __builtin_amdgcn_mfma_f32_16x16x32_bf16(af[j], bf[n], acc[j][n], 0, 0, 0);
        __builtin_amdgcn_s_setprio(0);
        SBAR();

        // ---- phase B: ds-read A half1; stage B(t+2); 16 MFMA
        #pragma unroll
        for (int j = 0; j < 4; ++j) af[j] = LD8(bufA, ((wrM * 128 + 64 + j * 16) * 64) + frbase);
        if (t2 < 32) STAGE(Bb, nB, t2);
        SBAR();
        asm volatile("s_waitcnt lgkmcnt(0)" ::: "memory");
        __builtin_amdgcn_sched_barrier(0);
        __builtin_amdgcn_s_setprio(1);
        #pragma unroll
        for (int j = 0; j < 4; ++j)
            #pragma unroll
            for (int n = 0; n < 4; ++n)
                acc[4 + j][n] = __builtin_amdgcn_mfma_f32_16x16x32_bf16(af[j], bf[n], acc[4 + j][n], 0, 0, 0);
        __builtin_amdgcn_s_setprio(0);
        // K-tile boundary: ensure t+1 landed; keep t+2's 4 loads in flight
        if (t < 30)       asm volatile("s_waitcnt vmcnt(4)" ::: "memory");
        else if (t == 30) asm volatile("s_waitcnt vmcnt(0)" ::: "memory");
        SBAR();
    }

    // ---- epilogue: affine + LDS bounce (64x260 fp32) + coalesced stores ----
    __syncthreads();
    float* cbuf = (float*)smem;
    const float bninv = rsqrtf(1.0f + 1e-3f);
    float alpha[4], addv[4];
    #pragma unroll
    for (int n = 0; n < 4; ++n) {
        const int col = tileN * 256 + wcn * 64 + n * 16 + fr;
        const float g = bg[col];
        alpha[n] = g * bninv;
        addv[n] = rb[col] * alpha[n] + bb[col];
    }
    const int srow = tid >> 3, cseg = (tid & 7) * 4;
    #pragma unroll
    for (int c = 0; c < 4; ++c) {
        if (wrM == (c >> 1)) {
            #pragma unroll
            for (int j = 0; j < 4; ++j) {
                const int mf = (c & 1) * 4 + j;
                const int lrow0 = j * 16 + kl * 4;
                #pragma unroll
                for (int n = 0; n < 4; ++n)
                    #pragma unroll
                    for (int r = 0; r < 4; ++r)
                        cbuf[(lrow0 + r) * 260 + wcn * 64 + n * 16 + fr] =
                            acc[mf][n][r] * alpha[n] + addv[n];
            }
        }
        __syncthreads();
        float* gptr = Cout + (long)z * 1048576 +
                      (long)(tileM * 256 + c * 64 + srow) * 1024 + tileN * 256;
        #pragma unroll
        for (int i = 0; i < 8; ++i)
            *(f32x4*)(gptr + cseg + i * 32) = *(const f32x4*)&cbuf[srow * 260 + cseg + i * 32];
        __syncthreads();
    }
}

// ---------------- NT bf16 GEMM (128x128, m97-style) for QK / PV / proj ----------------
// MODE 0: QK  (C *= SCALE)           -> bf16 C
// MODE 2: PV  (A is fp32 attn, reg-staged cvt; C offset from z) -> bf16 C
// MODE 3: proj (C += bias[col])      -> fp32 C (d_out)
template <int MODE>
__global__ __launch_bounds__(256) void gemm_nt(
    const void* __restrict__ Aall, const __hip_bfloat16* __restrict__ Ball,
    void* __restrict__ Call, int K,
    long sAz, long sBz, long sCz,
    const float* __restrict__ e0)
{
    constexpr bool AF32 = (MODE == 2);
    constexpr bool OF32 = (MODE == 3);

    __shared__ __align__(16) char smem[32 * 132 * 4];
    short* As = (short*)smem;
    short* Bs = (short*)(smem + 8192);
    float* cbuf = (float*)smem;

    const int tid = threadIdx.x;
    const int z = blockIdx.z;
    const int tileM = blockIdx.x, tileN = blockIdx.y;

    const short* AwB = nullptr;
    const float* AwF = nullptr;
    if constexpr (AF32) AwF = (const float*)Aall + sAz * z + (long)tileM * 128 * K;
    else                AwB = (const short*)Aall + sAz * z + (long)tileM * 128 * K;
    const short* Bw = (const short*)Ball + sBz * z + (long)tileN * 128 * K;

    const int r0s = tid >> 2, k0s = (tid & 3) * 8;
    const int r1s = r0s + 64;

    f32x4 acc[4][4];
    #pragma unroll
    for (int m = 0; m < 4; ++m)
        #pragma unroll
        for (int n = 0; n < 4; ++n) acc[m][n] = (f32x4){0.f, 0.f, 0.f, 0.f};

    const int lane = tid & 63;
    const int wave = tid >> 6;
    const int wr = (wave >> 1) * 64, wc = (wave & 1) * 64;
    const int fr = lane & 15;
    const int kb = (lane >> 4) * 8;

    const int nk = K >> 5;
    for (int kt = 0; kt < nk; ++kt) {
        if constexpr (AF32) {
            const float* Ak0 = AwF + (long)r0s * K + kt * 32 + k0s;
            const float* Ak1 = AwF + (long)r1s * K + kt * 32 + k0s;
            f32x4 a00 = *(const f32x4*)Ak0;
            f32x4 a01 = *(const f32x4*)(Ak0 + 4);
            f32x4 a10 = *(const f32x4*)Ak1;
            f32x4 a11 = *(const f32x4*)(Ak1 + 4);
            __syncthreads();
            short8 s0, s1;
            #pragma unroll
            for (int i = 0; i < 4; ++i) {
                s0[i] = (short)f2b_raw(a00[i]); s0[i + 4] = (short)f2b_raw(a01[i]);
                s1[i] = (short)f2b_raw(a10[i]); s1[i + 4] = (short)f2b_raw(a11[i]);
            }
            *(short8*)&As[tid * 8] = s0;
            *(short8*)&As[(tid + 256) * 8] = s1;
            gload_lds16(Bw + (long)r0s * K + kt * 32 + k0s, &Bs[tid * 8]);
            gload_lds16(Bw + (long)r1s * K + kt * 32 + k0s, &Bs[(tid + 256) * 8]);
            __syncthreads();
        } else {
            __syncthreads();
            gload_lds16(AwB + (long)r0s * K + kt * 32 + k0s, &As[tid * 8]);
            gload_lds16(AwB + (long)r1s * K + kt * 32 + k0s, &As[(tid + 256) * 8]);
            gload_lds16(Bw + (long)r0s * K + kt * 32 + k0s, &Bs[tid * 8]);
            gload_lds16(Bw + (long)r1s * K + kt * 32 + k0s, &Bs[(tid + 256) * 8]);
            __syncthreads();
        }

        short8 af[4], bf[4];
        #pragma unroll
        for (int m = 0; m < 4; ++m) af[m] = *(const short8*)&As[(wr + m * 16 + fr) * 32 + kb];
        #pragma unroll
        for (int n = 0; n < 4; ++n) bf[n] = *(const short8*)&Bs[(wc + n * 16 + fr) * 32 + kb];
        #pragma unroll
        for (int m = 0; m < 4; ++m)
            #pragma unroll
            for (int n = 0; n < 4; ++n)
                acc[m][n] = __builtin_amdgcn_mfma_f32_16x16x32_bf16(af[m], bf[n], acc[m][n], 0, 0, 0);
    }

    long cbase;
    if (MODE == 2) cbase = (long)(z >> 3) * 1048576 + (long)(z & 7) * 128;
    else           cbase = sCz * z;

    float alpha[4], addv[4];
    #pragma unroll
    for (int n = 0; n < 4; ++n) {
        const int col = tileN * 128 + wc + n * 16 + fr;
        float a_ = 1.f, b_ = 0.f;
        if (MODE == 0) a_ = 0.08838834764831843f;     // 128^-0.5
        if (MODE == 3) b_ = e0[col];
        alpha[n] = a_; addv[n] = b_;
    }

    __syncthreads();
    #pragma unroll
    for (int q = 0; q < 4; ++q) {
        if ((wave >> 1) == (q >> 1)) {
            #pragma unroll
            for (int mm = 0; mm < 2; ++mm) {
                const int m = (q & 1) * 2 + mm;
                const int lr0 = m * 16 + (lane >> 4) * 4 - (q & 1) * 32;
                #pragma unroll
                for (int n = 0; n < 4; ++n)
                    #pragma unroll
                    for (int r = 0; r < 4; ++r)
                        cbuf[(lr0 + r) * 132 + wc + n * 16 + fr] = acc[m][n][r] * alpha[n] + addv[n];
            }
        }
        __syncthreads();
        const long growbase = (long)tileM * 128 + q * 32;
        if constexpr (OF32) {
            float* Cg = (float*)Call + cbase;
            #pragma unroll
            for (int pass = 0; pass < 4; ++pass) {
                const int idx = (tid + pass * 256) * 4;
                const int row = idx >> 7, col = idx & 127;
                f32x4 v = *(const f32x4*)&cbuf[row * 132 + col];
                *(f32x4*)&Cg[(growbase + row) * 1024 + tileN * 128 + col] = v;
            }
        } else {
            __hip_bfloat16* Cg = (__hip_bfloat16*)Call + cbase;
            #pragma unroll
            for (int pass = 0; pass < 2; ++pass) {
                const int idx = (tid + pass * 256) * 8;
                const int row = idx >> 7, col = idx & 127;
                const float* src = &cbuf[row * 132 + col];
                f32x4 v0 = *(const f32x4*)src;
                f32x4 v1 = *(const f32x4*)(src + 4);
                short8 s;
                #pragma unroll
                for (int i = 0; i < 4; ++i) {
                    s[i] = (short)f2b_raw(v0[i]);
                    s[i + 4] = (short)f2b_raw(v1[i]);
                }
                *(short8*)&Cg[(growbase + row) * 1024 + tileN * 128 + col] = s;
            }
        }
        __syncthreads();
    }
}

extern "C" void kernel_launch(void* const* d_in, const int* in_sizes, int n_in,
                              void* d_out, int out_size, void* d_ws, size_t ws_size,
                              hipStream_t stream)
{
    const float* x  = (const float*)d_in[0];
    const float* qw = (const float*)d_in[1];
    const float* kw = (const float*)d_in[2];
    const float* vw = (const float*)d_in[3];
    const float* rw = (const float*)d_in[4];
    const float* rb = (const float*)d_in[5];
    const float* bg = (const float*)d_in[6];
    const float* bb = (const float*)d_in[7];
    const float* pw = (const float*)d_in[8];
    const float* pb = (const float*)d_in[9];

    float* outF  = (float*)d_out;          // [8,1024,1024] fp32
    float* attnF = outF + 8388608;         // [8,8,1024,1024] fp32

    // workspace (~222 MiB of ~1.15 GiB)
    char* w = (char*)d_ws;
    __hip_bfloat16* qb    = (__hip_bfloat16*)w; w += 16777216;    // [64,1024,128]
    __hip_bfloat16* kb    = (__hip_bfloat16*)w; w += 16777216;
    __hip_bfloat16* vb    = (__hip_bfloat16*)w; w += 16777216;
    __hip_bfloat16* vt    = (__hip_bfloat16*)w; w += 16777216;    // [64,128,1024]
    __hip_bfloat16* Wt    = (__hip_bfloat16*)w; w += 2097152;     // [1024,1024] reatten_w^T
    __hip_bfloat16* pWt   = (__hip_bfloat16*)w; w += 2097152;     // [1024,1024] proj_w^T
    __hip_bfloat16* o2    = (__hip_bfloat16*)w; w += 16777216;    // [8192,1024]
    __hip_bfloat16* S     = (__hip_bfloat16*)w; w += 134217728;   // [64,1024,1024]

    conv_qkv<<<8192, 256, 0, stream>>>(x, qw, kw, vw, qb, kb, vb);
    transpose_cast<float><<<dim3(32, 32, 1), 256, 0, stream>>>(rw, Wt, 1024, 1024, 0, 0);
    transpose_cast<float><<<dim3(32, 32, 1), 256, 0, stream>>>(pw, pWt, 1024, 1024, 0, 0);
    transpose_cast<__hip_bfloat16><<<dim3(4, 32, 64), 256, 0, stream>>>(vb, vt, 1024, 128, 131072, 131072);

    // S = q k^T * scale  (all 64 heads), bf16
    gemm_nt<0><<<dim3(8, 8, 64), 256, 0, stream>>>(
        qb, kb, S, 128, 131072, 131072, 1048576, nullptr);
    // row softmax in place
    softmax_inplace<<<65536, 256, 0, stream>>>(S);
    // attn = (P @ W + rb)*gamma/sqrt(1+eps) + beta -> fp32 d_out  (8-phase 256^2)
    gemm_reatten_256<<<dim3(4, 4, 64), 512, 0, stream>>>(S, Wt, attnF, bg, rb, bb);
    // o2[b, i, h*128+d] = attn @ v   (A = fp32 attn, reg-staged cvt)
    gemm_nt<2><<<dim3(8, 1, 64), 256, 0, stream>>>(
        attnF, vt, o2, 1024, 1048576, 131072, 0, nullptr);
    // out = o2 @ proj_w + proj_b  (fp32)
    gemm_nt<3><<<dim3(64, 8, 1), 256, 0, stream>>>(
        o2, pWt, outF, 1024, 0, 0, 0, pb);
}

// Round 7
// 405.914 us; speedup vs baseline: 1.8156x; 1.0440x over previous
//
#include <hip/hip_runtime.h>
#include <hip/hip_bf16.h>

typedef __attribute__((ext_vector_type(8))) short short8;
typedef __attribute__((ext_vector_type(4))) float f32x4;

__device__ __forceinline__ void gload_lds16(const void* g, void* l) {
    __builtin_amdgcn_global_load_lds(
        (const __attribute__((address_space(1))) void*)g,
        (__attribute__((address_space(3))) void*)l, 16, 0, 0);
}

__device__ __forceinline__ float gelu_exact(float x) {
    return 0.5f * x * (1.0f + erff(x * 0.70710678118654752f));
}
__device__ __forceinline__ float us2f(unsigned int u) {
    return __uint_as_float(u << 16);
}
__device__ __forceinline__ unsigned short f2b_raw(float f) {
    __hip_bfloat16 h = __float2bfloat16(f);
    return *reinterpret_cast<unsigned short*>(&h);
}
__device__ __forceinline__ float tofloat(float f) { return f; }
__device__ __forceinline__ float tofloat(__hip_bfloat16 h) { return __bfloat162float(h); }

// ---------------- conv 3x3 (C=1) + exact GELU over 32x32 patches ----------------
__global__ __launch_bounds__(256) void conv_qkv(
    const float* __restrict__ x,
    const float* __restrict__ qw, const float* __restrict__ kw, const float* __restrict__ vw,
    __hip_bfloat16* __restrict__ qb, __hip_bfloat16* __restrict__ kb, __hip_bfloat16* __restrict__ vb)
{
    __shared__ float img[1024];
    const int bid = blockIdx.x;            // b*1024 + n
    const int b = bid >> 10, n = bid & 1023;
    const float* xr = x + (long)bid * 1024;
    for (int i = threadIdx.x; i < 1024; i += 256) img[i] = xr[i];
    __syncthreads();

    float wq[9], wk[9], wv[9];
    #pragma unroll
    for (int i = 0; i < 9; ++i) { wq[i] = qw[i]; wk[i] = kw[i]; wv[i] = vw[i]; }

    for (int q = 0; q < 4; ++q) {
        const int p = q * 256 + threadIdx.x;    // 0..1023 spatial
        const int r = p >> 5, c = p & 31;
        float sq = 0.f, sk = 0.f, sv = 0.f;
        #pragma unroll
        for (int dy = 0; dy < 3; ++dy) {
            const int rr = r + dy - 1;
            if (rr < 0 || rr > 31) continue;
            #pragma unroll
            for (int dx = 0; dx < 3; ++dx) {
                const int cc = c + dx - 1;
                if (cc < 0 || cc > 31) continue;
                const float px = img[rr * 32 + cc];
                sq += px * wq[dy * 3 + dx];
                sk += px * wk[dy * 3 + dx];
                sv += px * wv[dy * 3 + dx];
            }
        }
        sq = gelu_exact(sq); sk = gelu_exact(sk); sv = gelu_exact(sv);
        const int h = p >> 7, d = p & 127;
        const long off = ((long)(b * 8 + h) * 1024 + n) * 128 + d;
        qb[off] = __float2bfloat16(sq);
        kb[off] = __float2bfloat16(sk);
        vb[off] = __float2bfloat16(sv);
    }
}

// ---------------- tiled transpose + cast to bf16 ----------------
template <typename Tin>
__global__ __launch_bounds__(256) void transpose_cast(
    const Tin* __restrict__ in, __hip_bfloat16* __restrict__ out,
    int R, int Cc, long inz, long outz)
{
    __shared__ float tile[32][33];
    const long z = blockIdx.z;
    const int c0 = blockIdx.x * 32, r0 = blockIdx.y * 32;
    const int tx = threadIdx.x & 31, ty = threadIdx.x >> 5;   // 32 x 8
    const Tin* ip = in + z * inz;
    #pragma unroll
    for (int i = 0; i < 32; i += 8)
        tile[ty + i][tx] = tofloat(ip[(long)(r0 + ty + i) * Cc + (c0 + tx)]);
    __syncthreads();
    __hip_bfloat16* op = out + z * outz;
    #pragma unroll
    for (int i = 0; i < 32; i += 8)
        op[(long)(c0 + ty + i) * R + (r0 + tx)] = __float2bfloat16(tile[tx][ty + i]);
}

// ---------------- in-place row softmax over [rows][1024] bf16 ----------------
__global__ __launch_bounds__(256) void softmax_inplace(__hip_bfloat16* __restrict__ S)
{
    __shared__ float red[8];
    const long row = blockIdx.x;
    uint2* p = reinterpret_cast<uint2*>(S + row * 1024);
    const int tid = threadIdx.x;
    uint2 u = p[tid];
    float v0 = us2f(u.x & 0xffffu), v1 = us2f(u.x >> 16);
    float v2 = us2f(u.y & 0xffffu), v3 = us2f(u.y >> 16);

    float m = fmaxf(fmaxf(v0, v1), fmaxf(v2, v3));
    for (int o = 32; o; o >>= 1) m = fmaxf(m, __shfl_xor(m, o));
    const int wave = tid >> 6, lane = tid & 63;
    if (lane == 0) red[wave] = m;
    __syncthreads();
    m = fmaxf(fmaxf(red[0], red[1]), fmaxf(red[2], red[3]));

    float e0 = expf(v0 - m), e1 = expf(v1 - m), e2 = expf(v2 - m), e3 = expf(v3 - m);
    float s = e0 + e1 + e2 + e3;
    for (int o = 32; o; o >>= 1) s += __shfl_xor(s, o);
    if (lane == 0) red[4 + wave] = s;
    __syncthreads();
    s = red[4] + red[5] + red[6] + red[7];
    const float inv = 1.0f / s;

    u.x = (unsigned int)f2b_raw(e0 * inv) | ((unsigned int)f2b_raw(e1 * inv) << 16);
    u.y = (unsigned int)f2b_raw(e2 * inv) | ((unsigned int)f2b_raw(e3 * inv) << 16);
    p[tid] = u;
}

// ---------------- reatten 256x256 GEMM, 1-barrier/K-tile counted-vmcnt ----------------
// C[z][1024][1024] fp32 (+ bf16 copy) = softmax(S)[z] @ Wt^T (NT), affine per col.
// 512 thr = 8 waves (2M x 4N), BK=32, 4 LDS K-tile buffers, stage t+2 while
// computing t, vmcnt(4) at K-tile end, XOR-swizzled LDS, compiler-managed lgkm.
__global__ __launch_bounds__(512, 2) void gemm_reatten_256(
    const __hip_bfloat16* __restrict__ Sall, const __hip_bfloat16* __restrict__ Wt,
    float* __restrict__ Cout, __hip_bfloat16* __restrict__ C2out,
    const float* __restrict__ bg, const float* __restrict__ rb, const float* __restrict__ bb)
{
    __shared__ __align__(16) char smem[131072];
    char* ldsA = smem;            // 4 x 16384 (A: [256 rows][32 k] bf16, swizzled)
    char* ldsB = smem + 65536;    // 4 x 16384

    const int tid = threadIdx.x;
    const int z = blockIdx.z, tileM = blockIdx.x, tileN = blockIdx.y;
    const char* Ab = (const char*)(Sall + (long)z * 1048576 + (long)tileM * 256 * 1024);
    const char* Bb = (const char*)(Wt + (long)tileN * 256 * 1024);

    // staging map: thread writes 2 linear 16B chunks; global src is inverse-swizzled
    int grow[2], goff[2], pphys[2];
    #pragma unroll
    for (int i = 0; i < 2; ++i) {
        const int p = i * 8192 + tid * 16;
        const int l = p ^ (((p >> 7) & 3) << 4);   // involution
        pphys[i] = p; grow[i] = l >> 6; goff[i] = l & 63;
    }
    auto STAGE = [&](const char* gb, char* lb, int kt) {
        #pragma unroll
        for (int i = 0; i < 2; ++i)
            gload_lds16(gb + (long)grow[i] * 2048 + kt * 64 + goff[i], lb + pphys[i]);
    };

    const int lane = tid & 63, wid = tid >> 6;
    const int wrM = wid >> 2, wcn = wid & 3;        // 2 x 4 wave grid
    const int fr = lane & 15, kl = lane >> 4;
    const int frbase = fr * 64 + kl * 16;           // logical byte of (row=fr, k=kl*8)

    auto LD8 = [&](const char* buf, int L) -> short8 {
        const int ph = L ^ (((L >> 7) & 3) << 4);   // swizzled read
        return *(const short8*)(buf + ph);
    };

    f32x4 acc[8][4];
    #pragma unroll
    for (int m = 0; m < 8; ++m)
        #pragma unroll
        for (int n = 0; n < 4; ++n) acc[m][n] = (f32x4){0.f, 0.f, 0.f, 0.f};

    // prologue: stage K-tiles 0,1
    STAGE(Ab, ldsA, 0);          STAGE(Bb, ldsB, 0);
    STAGE(Ab, ldsA + 16384, 1);  STAGE(Bb, ldsB + 16384, 1);
    asm volatile("s_waitcnt vmcnt(4)" ::: "memory");   // K-tile 0 landed
    __builtin_amdgcn_sched_barrier(0);
    __builtin_amdgcn_s_barrier();
    __builtin_amdgcn_sched_barrier(0);

    #pragma unroll 1
    for (int t = 0; t < 32; ++t) {
        char* bufA = ldsA + (t & 3) * 16384;
        char* bufB = ldsB + (t & 3) * 16384;
        const int t2 = t + 2;
        char* nA = ldsA + (t2 & 3) * 16384;
        char* nB = ldsB + (t2 & 3) * 16384;

        // lower half: B frags + A rows 0..63; stage A(t+2); 16 MFMA
        short8 bf[4], af[4], ag[4];
        #pragma unroll
        for (int n = 0; n < 4; ++n) bf[n] = LD8(bufB, ((wcn * 64 + n * 16) * 64) + frbase);
        #pragma unroll
        for (int j = 0; j < 4; ++j) af[j] = LD8(bufA, ((wrM * 128 + j * 16) * 64) + frbase);
        if (t2 < 32) STAGE(Ab, nA, t2);
        __builtin_amdgcn_s_setprio(1);
        #pragma unroll
        for (int j = 0; j < 4; ++j)
            #pragma unroll
            for (int n = 0; n < 4; ++n)
                acc[j][n] = __builtin_amdgcn_mfma_f32_16x16x32_bf16(af[j], bf[n], acc[j][n], 0, 0, 0);
        __builtin_amdgcn_s_setprio(0);

        // upper half: A rows 64..127; stage B(t+2); 16 MFMA
        #pragma unroll
        for (int j = 0; j < 4; ++j) ag[j] = LD8(bufA, ((wrM * 128 + 64 + j * 16) * 64) + frbase);
        if (t2 < 32) STAGE(Bb, nB, t2);
        __builtin_amdgcn_s_setprio(1);
        #pragma unroll
        for (int j = 0; j < 4; ++j)
            #pragma unroll
            for (int n = 0; n < 4; ++n)
                acc[4 + j][n] = __builtin_amdgcn_mfma_f32_16x16x32_bf16(ag[j], bf[n], acc[4 + j][n], 0, 0, 0);
        __builtin_amdgcn_s_setprio(0);

        // K-tile boundary: t+1 fully landed; t+2's 4 loads stay in flight
        if (t < 30)       { asm volatile("s_waitcnt vmcnt(4)" ::: "memory"); }
        else if (t == 30) { asm volatile("s_waitcnt vmcnt(0)" ::: "memory"); }
        __builtin_amdgcn_sched_barrier(0);
        __builtin_amdgcn_s_barrier();
        __builtin_amdgcn_sched_barrier(0);
    }

    // ---- epilogue: affine + LDS bounce (64x260 fp32) + coalesced dual stores ----
    __syncthreads();
    float* cbuf = (float*)smem;
    const float bninv = rsqrtf(1.0f + 1e-3f);
    float alpha[4], addv[4];
    #pragma unroll
    for (int n = 0; n < 4; ++n) {
        const int col = tileN * 256 + wcn * 64 + n * 16 + fr;
        const float g = bg[col];
        alpha[n] = g * bninv;
        addv[n] = rb[col] * alpha[n] + bb[col];
    }
    const int srow = tid >> 3, cseg = (tid & 7) * 4, c8 = (tid & 7) * 8;
    #pragma unroll
    for (int c = 0; c < 4; ++c) {
        if (wrM == (c >> 1)) {
            #pragma unroll
            for (int j = 0; j < 4; ++j) {
                const int mf = (c & 1) * 4 + j;
                const int lrow0 = j * 16 + kl * 4;
                #pragma unroll
                for (int n = 0; n < 4; ++n)
                    #pragma unroll
                    for (int r = 0; r < 4; ++r)
                        cbuf[(lrow0 + r) * 260 + wcn * 64 + n * 16 + fr] =
                            acc[mf][n][r] * alpha[n] + addv[n];
            }
        }
        __syncthreads();
        const long gro = (long)(tileM * 256 + c * 64 + srow);
        float* gp = Cout + (long)z * 1048576 + gro * 1024 + tileN * 256;
        #pragma unroll
        for (int i = 0; i < 8; ++i)
            *(f32x4*)(gp + cseg + i * 32) = *(const f32x4*)&cbuf[srow * 260 + cseg + i * 32];
        __hip_bfloat16* gp2 = C2out + (long)z * 1048576 + gro * 1024 + tileN * 256;
        #pragma unroll
        for (int i = 0; i < 4; ++i) {
            const float* src = &cbuf[srow * 260 + c8 + i * 64];
            f32x4 v0 = *(const f32x4*)src;
            f32x4 v1 = *(const f32x4*)(src + 4);
            short8 s;
            #pragma unroll
            for (int k = 0; k < 4; ++k) {
                s[k] = (short)f2b_raw(v0[k]);
                s[k + 4] = (short)f2b_raw(v1[k]);
            }
            *(short8*)(gp2 + c8 + i * 64) = s;
        }
        __syncthreads();
    }
}

// ---------------- NT bf16 GEMM (128x128, m97-style) for QK / PV / proj ----------------
// MODE 0: QK  (C *= SCALE)           -> bf16 C
// MODE 2: PV  (C offset from z)      -> bf16 C
// MODE 3: proj (C += bias[col])      -> fp32 C (d_out)
template <int MODE>
__global__ __launch_bounds__(256) void gemm_nt(
    const __hip_bfloat16* __restrict__ Aall, const __hip_bfloat16* __restrict__ Ball,
    void* __restrict__ Call, int K,
    long sAz, long sBz, long sCz,
    const float* __restrict__ e0)
{
    constexpr bool OF32 = (MODE == 3);

    __shared__ __align__(16) char smem[32 * 132 * 4];
    short* As = (short*)smem;
    short* Bs = (short*)(smem + 8192);
    float* cbuf = (float*)smem;

    const int tid = threadIdx.x;
    const int z = blockIdx.z;
    const int tileM = blockIdx.x, tileN = blockIdx.y;

    const short* Aw = (const short*)Aall + sAz * z + (long)tileM * 128 * K;
    const short* Bw = (const short*)Ball + sBz * z + (long)tileN * 128 * K;

    const int r0s = tid >> 2, k0s = (tid & 3) * 8;
    const int r1s = r0s + 64;

    f32x4 acc[4][4];
    #pragma unroll
    for (int m = 0; m < 4; ++m)
        #pragma unroll
        for (int n = 0; n < 4; ++n) acc[m][n] = (f32x4){0.f, 0.f, 0.f, 0.f};

    const int lane = tid & 63;
    const int wave = tid >> 6;
    const int wr = (wave >> 1) * 64, wc = (wave & 1) * 64;
    const int fr = lane & 15;
    const int kb = (lane >> 4) * 8;

    const int nk = K >> 5;
    for (int kt = 0; kt < nk; ++kt) {
        __syncthreads();
        gload_lds16(Aw + (long)r0s * K + kt * 32 + k0s, &As[tid * 8]);
        gload_lds16(Aw + (long)r1s * K + kt * 32 + k0s, &As[(tid + 256) * 8]);
        gload_lds16(Bw + (long)r0s * K + kt * 32 + k0s, &Bs[tid * 8]);
        gload_lds16(Bw + (long)r1s * K + kt * 32 + k0s, &Bs[(tid + 256) * 8]);
        __syncthreads();

        short8 af[4], bf[4];
        #pragma unroll
        for (int m = 0; m < 4; ++m) af[m] = *(const short8*)&As[(wr + m * 16 + fr) * 32 + kb];
        #pragma unroll
        for (int n = 0; n < 4; ++n) bf[n] = *(const short8*)&Bs[(wc + n * 16 + fr) * 32 + kb];
        #pragma unroll
        for (int m = 0; m < 4; ++m)
            #pragma unroll
            for (int n = 0; n < 4; ++n)
                acc[m][n] = __builtin_amdgcn_mfma_f32_16x16x32_bf16(af[m], bf[n], acc[m][n], 0, 0, 0);
    }

    long cbase;
    if (MODE == 2) cbase = (long)(z >> 3) * 1048576 + (long)(z & 7) * 128;
    else           cbase = sCz * z;

    float alpha[4], addv[4];
    #pragma unroll
    for (int n = 0; n < 4; ++n) {
        const int col = tileN * 128 + wc + n * 16 + fr;
        float a_ = 1.f, b_ = 0.f;
        if (MODE == 0) a_ = 0.08838834764831843f;     // 128^-0.5
        if (MODE == 3) b_ = e0[col];
        alpha[n] = a_; addv[n] = b_;
    }

    __syncthreads();
    #pragma unroll
    for (int q = 0; q < 4; ++q) {
        if ((wave >> 1) == (q >> 1)) {
            #pragma unroll
            for (int mm = 0; mm < 2; ++mm) {
                const int m = (q & 1) * 2 + mm;
                const int lr0 = m * 16 + (lane >> 4) * 4 - (q & 1) * 32;
                #pragma unroll
                for (int n = 0; n < 4; ++n)
                    #pragma unroll
                    for (int r = 0; r < 4; ++r)
                        cbuf[(lr0 + r) * 132 + wc + n * 16 + fr] = acc[m][n][r] * alpha[n] + addv[n];
            }
        }
        __syncthreads();
        const long growbase = (long)tileM * 128 + q * 32;
        if constexpr (OF32) {
            float* Cg = (float*)Call + cbase;
            #pragma unroll
            for (int pass = 0; pass < 4; ++pass) {
                const int idx = (tid + pass * 256) * 4;
                const int row = idx >> 7, col = idx & 127;
                f32x4 v = *(const f32x4*)&cbuf[row * 132 + col];
                *(f32x4*)&Cg[(growbase + row) * 1024 + tileN * 128 + col] = v;
            }
        } else {
            __hip_bfloat16* Cg = (__hip_bfloat16*)Call + cbase;
            #pragma unroll
            for (int pass = 0; pass < 2; ++pass) {
                const int idx = (tid + pass * 256) * 8;
                const int row = idx >> 7, col = idx & 127;
                const float* src = &cbuf[row * 132 + col];
                f32x4 v0 = *(const f32x4*)src;
                f32x4 v1 = *(const f32x4*)(src + 4);
                short8 s;
                #pragma unroll
                for (int i = 0; i < 4; ++i) {
                    s[i] = (short)f2b_raw(v0[i]);
                    s[i + 4] = (short)f2b_raw(v1[i]);
                }
                *(short8*)&Cg[(growbase + row) * 1024 + tileN * 128 + col] = s;
            }
        }
        __syncthreads();
    }
}

extern "C" void kernel_launch(void* const* d_in, const int* in_sizes, int n_in,
                              void* d_out, int out_size, void* d_ws, size_t ws_size,
                              hipStream_t stream)
{
    const float* x  = (const float*)d_in[0];
    const float* qw = (const float*)d_in[1];
    const float* kw = (const float*)d_in[2];
    const float* vw = (const float*)d_in[3];
    const float* rw = (const float*)d_in[4];
    const float* rb = (const float*)d_in[5];
    const float* bg = (const float*)d_in[6];
    const float* bb = (const float*)d_in[7];
    const float* pw = (const float*)d_in[8];
    const float* pb = (const float*)d_in[9];

    float* outF  = (float*)d_out;          // [8,1024,1024] fp32
    float* attnF = outF + 8388608;         // [8,8,1024,1024] fp32

    // workspace (~356 MiB of ~1.15 GiB)
    char* w = (char*)d_ws;
    __hip_bfloat16* qb    = (__hip_bfloat16*)w; w += 16777216;    // [64,1024,128]
    __hip_bfloat16* kb    = (__hip_bfloat16*)w; w += 16777216;
    __hip_bfloat16* vb    = (__hip_bfloat16*)w; w += 16777216;
    __hip_bfloat16* vt    = (__hip_bfloat16*)w; w += 16777216;    // [64,128,1024]
    __hip_bfloat16* Wt    = (__hip_bfloat16*)w; w += 2097152;     // [1024,1024] reatten_w^T
    __hip_bfloat16* pWt   = (__hip_bfloat16*)w; w += 2097152;     // [1024,1024] proj_w^T
    __hip_bfloat16* o2    = (__hip_bfloat16*)w; w += 16777216;    // [8192,1024]
    __hip_bfloat16* S     = (__hip_bfloat16*)w; w += 134217728;   // [64,1024,1024]
    __hip_bfloat16* attnb = (__hip_bfloat16*)w; w += 134217728;   // [64,1024,1024]

    conv_qkv<<<8192, 256, 0, stream>>>(x, qw, kw, vw, qb, kb, vb);
    transpose_cast<float><<<dim3(32, 32, 1), 256, 0, stream>>>(rw, Wt, 1024, 1024, 0, 0);
    transpose_cast<float><<<dim3(32, 32, 1), 256, 0, stream>>>(pw, pWt, 1024, 1024, 0, 0);
    transpose_cast<__hip_bfloat16><<<dim3(4, 32, 64), 256, 0, stream>>>(vb, vt, 1024, 128, 131072, 131072);

    // S = q k^T * scale  (all 64 heads), bf16
    gemm_nt<0><<<dim3(8, 8, 64), 256, 0, stream>>>(
        qb, kb, S, 128, 131072, 131072, 1048576, nullptr);
    // row softmax in place
    softmax_inplace<<<65536, 256, 0, stream>>>(S);
    // attn = (P @ W + rb)*gamma/sqrt(1+eps) + beta -> fp32 d_out + bf16 ws
    gemm_reatten_256<<<dim3(4, 4, 64), 512, 0, stream>>>(S, Wt, attnF, attnb, bg, rb, bb);
    // o2[b, i, h*128+d] = attn @ v   (bf16 A via global_load_lds)
    gemm_nt<2><<<dim3(8, 1, 64), 256, 0, stream>>>(
        attnb, vt, o2, 1024, 1048576, 131072, 0, nullptr);
    // out = o2 @ proj_w + proj_b  (fp32)
    gemm_nt<3><<<dim3(64, 8, 1), 256, 0, stream>>>(
        o2, pWt, outF, 1024, 0, 0, 0, pb);
}

// Round 8
// 372.162 us; speedup vs baseline: 1.9803x; 1.0907x over previous
//
#include <hip/hip_runtime.h>
#include <hip/hip_bf16.h>

typedef __attribute__((ext_vector_type(8))) short short8;
typedef __attribute__((ext_vector_type(4))) float f32x4;

__device__ __forceinline__ void gload_lds16(const void* g, void* l) {
    __builtin_amdgcn_global_load_lds(
        (const __attribute__((address_space(1))) void*)g,
        (__attribute__((address_space(3))) void*)l, 16, 0, 0);
}

__device__ __forceinline__ float gelu_exact(float x) {
    return 0.5f * x * (1.0f + erff(x * 0.70710678118654752f));
}
__device__ __forceinline__ unsigned short f2b_raw(float f) {
    __hip_bfloat16 h = __float2bfloat16(f);
    return *reinterpret_cast<unsigned short*>(&h);
}
__device__ __forceinline__ float tofloat(float f) { return f; }
__device__ __forceinline__ float tofloat(__hip_bfloat16 h) { return __bfloat162float(h); }

// ---------------- conv 3x3 (C=1) + exact GELU over 32x32 patches ----------------
__global__ __launch_bounds__(256) void conv_qkv(
    const float* __restrict__ x,
    const float* __restrict__ qw, const float* __restrict__ kw, const float* __restrict__ vw,
    __hip_bfloat16* __restrict__ qb, __hip_bfloat16* __restrict__ kb, __hip_bfloat16* __restrict__ vb)
{
    __shared__ float img[1024];
    const int bid = blockIdx.x;            // b*1024 + n
    const int b = bid >> 10, n = bid & 1023;
    const float* xr = x + (long)bid * 1024;
    for (int i = threadIdx.x; i < 1024; i += 256) img[i] = xr[i];
    __syncthreads();

    float wq[9], wk[9], wv[9];
    #pragma unroll
    for (int i = 0; i < 9; ++i) { wq[i] = qw[i]; wk[i] = kw[i]; wv[i] = vw[i]; }

    for (int q = 0; q < 4; ++q) {
        const int p = q * 256 + threadIdx.x;    // 0..1023 spatial
        const int r = p >> 5, c = p & 31;
        float sq = 0.f, sk = 0.f, sv = 0.f;
        #pragma unroll
        for (int dy = 0; dy < 3; ++dy) {
            const int rr = r + dy - 1;
            if (rr < 0 || rr > 31) continue;
            #pragma unroll
            for (int dx = 0; dx < 3; ++dx) {
                const int cc = c + dx - 1;
                if (cc < 0 || cc > 31) continue;
                const float px = img[rr * 32 + cc];
                sq += px * wq[dy * 3 + dx];
                sk += px * wk[dy * 3 + dx];
                sv += px * wv[dy * 3 + dx];
            }
        }
        sq = gelu_exact(sq); sk = gelu_exact(sk); sv = gelu_exact(sv);
        const int h = p >> 7, d = p & 127;
        const long off = ((long)(b * 8 + h) * 1024 + n) * 128 + d;
        qb[off] = __float2bfloat16(sq);
        kb[off] = __float2bfloat16(sk);
        vb[off] = __float2bfloat16(sv);
    }
}

// ---------------- tiled transpose + cast to bf16 ----------------
template <typename Tin>
__global__ __launch_bounds__(256) void transpose_cast(
    const Tin* __restrict__ in, __hip_bfloat16* __restrict__ out,
    int R, int Cc, long inz, long outz)
{
    __shared__ float tile[32][33];
    const long z = blockIdx.z;
    const int c0 = blockIdx.x * 32, r0 = blockIdx.y * 32;
    const int tx = threadIdx.x & 31, ty = threadIdx.x >> 5;   // 32 x 8
    const Tin* ip = in + z * inz;
    #pragma unroll
    for (int i = 0; i < 32; i += 8)
        tile[ty + i][tx] = tofloat(ip[(long)(r0 + ty + i) * Cc + (c0 + tx)]);
    __syncthreads();
    __hip_bfloat16* op = out + z * outz;
    #pragma unroll
    for (int i = 0; i < 32; i += 8)
        op[(long)(c0 + ty + i) * R + (r0 + tx)] = __float2bfloat16(tile[tx][ty + i]);
}

// ---------------- fused QK^T + exp (softmax numerator) + row-sum ----------------
// Per block: rows [rt*128, rt*128+128) of head z. P_un = exp(scale * q k^T) bf16,
// linv[z][row] = 1/sum_j P_un. Softmax(x) == e^x / sum(e^x); max-shift omitted
// (|S| bounded; fp32 exp exact-safe). 1/l folded into reatten epilogue.
__global__ __launch_bounds__(256, 2) void qk_softmax(
    const __hip_bfloat16* __restrict__ qb, const __hip_bfloat16* __restrict__ kb,
    __hip_bfloat16* __restrict__ Pun, float* __restrict__ linv)
{
    __shared__ __align__(16) char smem[74240];
    char* As = smem;                                       // [128][128] bf16 swizzled
    char* Bs = smem + 32768;                               // [128][128] bf16 swizzled
    __hip_bfloat16* pbuf = (__hip_bfloat16*)(smem + 65536); // [32][136] bounce
    float* lred = (float*)(smem + 65536);                  // reuse after last bounce

    const int tid = threadIdx.x;
    const int rt = blockIdx.x, z = blockIdx.y;
    const char* Ag = (const char*)(qb + ((long)z * 1024 + rt * 128) * 128);
    const char* Bg = (const char*)(kb + (long)z * 1024 * 128);

    // staging map: linear LDS dest, inverse-swizzled global source (rule #21)
    int gsrc[8], pphys[8];
    #pragma unroll
    for (int i = 0; i < 8; ++i) {
        const int p = i * 4096 + tid * 16;
        const int L = p ^ (((p >> 8) & 7) << 4);   // involution (row bits0-2 -> byte bits4-6)
        pphys[i] = p; gsrc[i] = L;                 // L = row*256 + kbyte, global layout matches
    }
    auto STAGE = [&](const char* gb, char* lb) {
        #pragma unroll
        for (int i = 0; i < 8; ++i) gload_lds16(gb + gsrc[i], lb + pphys[i]);
    };
    auto LD8 = [&](const char* buf, int L) -> short8 {
        const int ph = L ^ (((L >> 8) & 7) << 4);
        return *(const short8*)(buf + ph);
    };

    const int lane = tid & 63, wave = tid >> 6;
    const int wr = (wave >> 1) * 64, wc = (wave & 1) * 64;
    const int fr = lane & 15, kl = lane >> 4;

    STAGE(Ag, As);
    STAGE(Bg, Bs);
    __syncthreads();

    short8 af[4][4];
    #pragma unroll
    for (int m = 0; m < 4; ++m)
        #pragma unroll
        for (int kk = 0; kk < 4; ++kk)
            af[m][kk] = LD8(As, (wr + m * 16 + fr) * 256 + (kl * 8 + kk * 32) * 2);

    float lacc[4][4];
    #pragma unroll
    for (int m = 0; m < 4; ++m)
        #pragma unroll
        for (int r = 0; r < 4; ++r) lacc[m][r] = 0.f;

    const float SCALE = 0.08838834764831843f;   // 128^-0.5

    for (int c = 0; c < 8; ++c) {
        f32x4 acc[4][4];
        #pragma unroll
        for (int m = 0; m < 4; ++m)
            #pragma unroll
            for (int n = 0; n < 4; ++n) acc[m][n] = (f32x4){0.f, 0.f, 0.f, 0.f};

        #pragma unroll
        for (int kk = 0; kk < 4; ++kk) {
            short8 bf[4];
            #pragma unroll
            for (int n = 0; n < 4; ++n)
                bf[n] = LD8(Bs, (wc + n * 16 + fr) * 256 + (kl * 8 + kk * 32) * 2);
            #pragma unroll
            for (int m = 0; m < 4; ++m)
                #pragma unroll
                for (int n = 0; n < 4; ++n)
                    acc[m][n] = __builtin_amdgcn_mfma_f32_16x16x32_bf16(af[m][kk], bf[n], acc[m][n], 0, 0, 0);
        }

        // exp in-register + row-sum accumulate
        #pragma unroll
        for (int m = 0; m < 4; ++m) {
            #pragma unroll
            for (int n = 0; n < 4; ++n)
                #pragma unroll
                for (int r = 0; r < 4; ++r)
                    acc[m][n][r] = __expf(acc[m][n][r] * SCALE) * 0.f + expf(acc[m][n][r] * SCALE);
            #pragma unroll
            for (int r = 0; r < 4; ++r)
                lacc[m][r] += (acc[m][0][r] + acc[m][1][r]) + (acc[m][2][r] + acc[m][3][r]);
        }

        // bounce 32-row rounds -> coalesced bf16 stores
        #pragma unroll
        for (int q2 = 0; q2 < 4; ++q2) {
            if ((wave >> 1) == (q2 >> 1)) {
                #pragma unroll
                for (int mm = 0; mm < 2; ++mm) {
                    const int m = (q2 & 1) * 2 + mm;
                    const int lr0 = m * 16 + kl * 4 - (q2 & 1) * 32;
                    #pragma unroll
                    for (int n = 0; n < 4; ++n)
                        #pragma unroll
                        for (int r = 0; r < 4; ++r)
                            pbuf[(lr0 + r) * 136 + wc + n * 16 + fr] = __float2bfloat16(acc[m][n][r]);
                }
            }
            __syncthreads();
            #pragma unroll
            for (int p = 0; p < 2; ++p) {
                const int idx = (tid + p * 256) * 8;
                const int row = idx >> 7, col = idx & 127;
                short8 s = *(const short8*)&pbuf[row * 136 + col];
                *(short8*)&Pun[((long)z * 1024 + rt * 128 + q2 * 32 + row) * 1024 + c * 128 + col] = s;
            }
            __syncthreads();
        }

        if (c < 7) {
            STAGE(Bg + (c + 1) * 32768, Bs);
            __syncthreads();
        }
    }

    // l reduction: sum over 16 fr-lanes, then across the 2 col-half waves via LDS
    #pragma unroll
    for (int m = 0; m < 4; ++m)
        #pragma unroll
        for (int r = 0; r < 4; ++r) {
            float v = lacc[m][r];
            v += __shfl_xor(v, 1); v += __shfl_xor(v, 2);
            v += __shfl_xor(v, 4); v += __shfl_xor(v, 8);
            lacc[m][r] = v;
        }
    __syncthreads();
    if (fr == 0) {
        #pragma unroll
        for (int m = 0; m < 4; ++m)
            #pragma unroll
            for (int r = 0; r < 4; ++r)
                lred[(wr + m * 16 + kl * 4 + r) * 2 + (wave & 1)] = lacc[m][r];
    }
    __syncthreads();
    if (tid < 128) {
        const float s = lred[tid * 2] + lred[tid * 2 + 1];
        linv[(long)z * 1024 + rt * 128 + tid] = 1.0f / s;
    }
}

// ---------------- reatten 256x256 GEMM, 1-barrier/K-tile counted-vmcnt ----------------
// C[z] fp32 (+ bf16 copy) = (P_un[z] @ Wt^T) * (1/l_row) * alphaBN + addvBN.
__global__ __launch_bounds__(512, 2) void gemm_reatten_256(
    const __hip_bfloat16* __restrict__ Sall, const __hip_bfloat16* __restrict__ Wt,
    float* __restrict__ Cout, __hip_bfloat16* __restrict__ C2out,
    const float* __restrict__ bg, const float* __restrict__ rb, const float* __restrict__ bb,
    const float* __restrict__ linv)
{
    __shared__ __align__(16) char smem[131072];
    char* ldsA = smem;            // 4 x 16384 (A: [256 rows][32 k] bf16, swizzled)
    char* ldsB = smem + 65536;    // 4 x 16384

    const int tid = threadIdx.x;
    const int z = blockIdx.z, tileM = blockIdx.x, tileN = blockIdx.y;
    const char* Ab = (const char*)(Sall + (long)z * 1048576 + (long)tileM * 256 * 1024);
    const char* Bb = (const char*)(Wt + (long)tileN * 256 * 1024);

    int grow[2], goff[2], pphys[2];
    #pragma unroll
    for (int i = 0; i < 2; ++i) {
        const int p = i * 8192 + tid * 16;
        const int l = p ^ (((p >> 7) & 3) << 4);   // involution
        pphys[i] = p; grow[i] = l >> 6; goff[i] = l & 63;
    }
    auto STAGE = [&](const char* gb, char* lb, int kt) {
        #pragma unroll
        for (int i = 0; i < 2; ++i)
            gload_lds16(gb + (long)grow[i] * 2048 + kt * 64 + goff[i], lb + pphys[i]);
    };

    const int lane = tid & 63, wid = tid >> 6;
    const int wrM = wid >> 2, wcn = wid & 3;        // 2 x 4 wave grid
    const int fr = lane & 15, kl = lane >> 4;
    const int frbase = fr * 64 + kl * 16;

    auto LD8 = [&](const char* buf, int L) -> short8 {
        const int ph = L ^ (((L >> 7) & 3) << 4);
        return *(const short8*)(buf + ph);
    };

    f32x4 acc[8][4];
    #pragma unroll
    for (int m = 0; m < 8; ++m)
        #pragma unroll
        for (int n = 0; n < 4; ++n) acc[m][n] = (f32x4){0.f, 0.f, 0.f, 0.f};

    STAGE(Ab, ldsA, 0);          STAGE(Bb, ldsB, 0);
    STAGE(Ab, ldsA + 16384, 1);  STAGE(Bb, ldsB + 16384, 1);
    asm volatile("s_waitcnt vmcnt(4)" ::: "memory");
    __builtin_amdgcn_sched_barrier(0);
    __builtin_amdgcn_s_barrier();
    __builtin_amdgcn_sched_barrier(0);

    #pragma unroll 1
    for (int t = 0; t < 32; ++t) {
        char* bufA = ldsA + (t & 3) * 16384;
        char* bufB = ldsB + (t & 3) * 16384;
        const int t2 = t + 2;
        char* nA = ldsA + (t2 & 3) * 16384;
        char* nB = ldsB + (t2 & 3) * 16384;

        short8 bf[4], af[4], ag[4];
        #pragma unroll
        for (int n = 0; n < 4; ++n) bf[n] = LD8(bufB, ((wcn * 64 + n * 16) * 64) + frbase);
        #pragma unroll
        for (int j = 0; j < 4; ++j) af[j] = LD8(bufA, ((wrM * 128 + j * 16) * 64) + frbase);
        if (t2 < 32) STAGE(Ab, nA, t2);
        __builtin_amdgcn_s_setprio(1);
        #pragma unroll
        for (int j = 0; j < 4; ++j)
            #pragma unroll
            for (int n = 0; n < 4; ++n)
                acc[j][n] = __builtin_amdgcn_mfma_f32_16x16x32_bf16(af[j], bf[n], acc[j][n], 0, 0, 0);
        __builtin_amdgcn_s_setprio(0);

        #pragma unroll
        for (int j = 0; j < 4; ++j) ag[j] = LD8(bufA, ((wrM * 128 + 64 + j * 16) * 64) + frbase);
        if (t2 < 32) STAGE(Bb, nB, t2);
        __builtin_amdgcn_s_setprio(1);
        #pragma unroll
        for (int j = 0; j < 4; ++j)
            #pragma unroll
            for (int n = 0; n < 4; ++n)
                acc[4 + j][n] = __builtin_amdgcn_mfma_f32_16x16x32_bf16(ag[j], bf[n], acc[4 + j][n], 0, 0, 0);
        __builtin_amdgcn_s_setprio(0);

        if (t < 30)       { asm volatile("s_waitcnt vmcnt(4)" ::: "memory"); }
        else if (t == 30) { asm volatile("s_waitcnt vmcnt(0)" ::: "memory"); }
        __builtin_amdgcn_sched_barrier(0);
        __builtin_amdgcn_s_barrier();
        __builtin_amdgcn_sched_barrier(0);
    }

    // ---- epilogue: row-scale (1/l) + BN affine + LDS bounce + dual stores ----
    __syncthreads();
    float* cbuf = (float*)smem;
    const float bninv = rsqrtf(1.0f + 1e-3f);
    float alpha[4], addv[4];
    #pragma unroll
    for (int n = 0; n < 4; ++n) {
        const int col = tileN * 256 + wcn * 64 + n * 16 + fr;
        const float g = bg[col];
        alpha[n] = g * bninv;
        addv[n] = rb[col] * alpha[n] + bb[col];
    }
    const float* linvz = linv + (long)z * 1024 + tileM * 256 + wrM * 128 + kl * 4;
    float lr[8][4];
    #pragma unroll
    for (int mf = 0; mf < 8; ++mf)
        #pragma unroll
        for (int r = 0; r < 4; ++r) lr[mf][r] = linvz[mf * 16 + r];

    const int srow = tid >> 3, cseg = (tid & 7) * 4, c8 = (tid & 7) * 8;
    #pragma unroll
    for (int c = 0; c < 4; ++c) {
        if (wrM == (c >> 1)) {
            #pragma unroll
            for (int j = 0; j < 4; ++j) {
                const int mf = (c & 1) * 4 + j;
                const int lrow0 = j * 16 + kl * 4;
                #pragma unroll
                for (int n = 0; n < 4; ++n)
                    #pragma unroll
                    for (int r = 0; r < 4; ++r)
                        cbuf[(lrow0 + r) * 260 + wcn * 64 + n * 16 + fr] =
                            acc[mf][n][r] * (lr[mf][r] * alpha[n]) + addv[n];
            }
        }
        __syncthreads();
        const long gro = (long)(tileM * 256 + c * 64 + srow);
        float* gp = Cout + (long)z * 1048576 + gro * 1024 + tileN * 256;
        #pragma unroll
        for (int i = 0; i < 8; ++i)
            *(f32x4*)(gp + cseg + i * 32) = *(const f32x4*)&cbuf[srow * 260 + cseg + i * 32];
        __hip_bfloat16* gp2 = C2out + (long)z * 1048576 + gro * 1024 + tileN * 256;
        #pragma unroll
        for (int i = 0; i < 4; ++i) {
            const float* src = &cbuf[srow * 260 + c8 + i * 64];
            f32x4 v0 = *(const f32x4*)src;
            f32x4 v1 = *(const f32x4*)(src + 4);
            short8 s;
            #pragma unroll
            for (int k = 0; k < 4; ++k) {
                s[k] = (short)f2b_raw(v0[k]);
                s[k + 4] = (short)f2b_raw(v1[k]);
            }
            *(short8*)(gp2 + c8 + i * 64) = s;
        }
        __syncthreads();
    }
}

// ---------------- NT bf16 GEMM (128x128, m97-style) for PV / proj ----------------
// MODE 2: PV  (C offset from z)      -> bf16 C
// MODE 3: proj (C += bias[col])      -> fp32 C (d_out)
template <int MODE>
__global__ __launch_bounds__(256) void gemm_nt(
    const __hip_bfloat16* __restrict__ Aall, const __hip_bfloat16* __restrict__ Ball,
    void* __restrict__ Call, int K,
    long sAz, long sBz, long sCz,
    const float* __restrict__ e0)
{
    constexpr bool OF32 = (MODE == 3);

    __shared__ __align__(16) char smem[32 * 132 * 4];
    short* As = (short*)smem;
    short* Bs = (short*)(smem + 8192);
    float* cbuf = (float*)smem;

    const int tid = threadIdx.x;
    const int z = blockIdx.z;
    const int tileM = blockIdx.x, tileN = blockIdx.y;

    const short* Aw = (const short*)Aall + sAz * z + (long)tileM * 128 * K;
    const short* Bw = (const short*)Ball + sBz * z + (long)tileN * 128 * K;

    const int r0s = tid >> 2, k0s = (tid & 3) * 8;
    const int r1s = r0s + 64;

    f32x4 acc[4][4];
    #pragma unroll
    for (int m = 0; m < 4; ++m)
        #pragma unroll
        for (int n = 0; n < 4; ++n) acc[m][n] = (f32x4){0.f, 0.f, 0.f, 0.f};

    const int lane = tid & 63;
    const int wave = tid >> 6;
    const int wr = (wave >> 1) * 64, wc = (wave & 1) * 64;
    const int fr = lane & 15;
    const int kb = (lane >> 4) * 8;

    const int nk = K >> 5;
    for (int kt = 0; kt < nk; ++kt) {
        __syncthreads();
        gload_lds16(Aw + (long)r0s * K + kt * 32 + k0s, &As[tid * 8]);
        gload_lds16(Aw + (long)r1s * K + kt * 32 + k0s, &As[(tid + 256) * 8]);
        gload_lds16(Bw + (long)r0s * K + kt * 32 + k0s, &Bs[tid * 8]);
        gload_lds16(Bw + (long)r1s * K + kt * 32 + k0s, &Bs[(tid + 256) * 8]);
        __syncthreads();

        short8 af[4], bf[4];
        #pragma unroll
        for (int m = 0; m < 4; ++m) af[m] = *(const short8*)&As[(wr + m * 16 + fr) * 32 + kb];
        #pragma unroll
        for (int n = 0; n < 4; ++n) bf[n] = *(const short8*)&Bs[(wc + n * 16 + fr) * 32 + kb];
        #pragma unroll
        for (int m = 0; m < 4; ++m)
            #pragma unroll
            for (int n = 0; n < 4; ++n)
                acc[m][n] = __builtin_amdgcn_mfma_f32_16x16x32_bf16(af[m], bf[n], acc[m][n], 0, 0, 0);
    }

    long cbase;
    if (MODE == 2) cbase = (long)(z >> 3) * 1048576 + (long)(z & 7) * 128;
    else           cbase = sCz * z;

    float addv[4];
    #pragma unroll
    for (int n = 0; n < 4; ++n) {
        const int col = tileN * 128 + wc + n * 16 + fr;
        addv[n] = (MODE == 3) ? e0[col] : 0.f;
    }

    __syncthreads();
    #pragma unroll
    for (int q = 0; q < 4; ++q) {
        if ((wave >> 1) == (q >> 1)) {
            #pragma unroll
            for (int mm = 0; mm < 2; ++mm) {
                const int m = (q & 1) * 2 + mm;
                const int lr0 = m * 16 + (lane >> 4) * 4 - (q & 1) * 32;
                #pragma unroll
                for (int n = 0; n < 4; ++n)
                    #pragma unroll
                    for (int r = 0; r < 4; ++r)
                        cbuf[(lr0 + r) * 132 + wc + n * 16 + fr] = acc[m][n][r] + addv[n];
            }
        }
        __syncthreads();
        const long growbase = (long)tileM * 128 + q * 32;
        if constexpr (OF32) {
            float* Cg = (float*)Call + cbase;
            #pragma unroll
            for (int pass = 0; pass < 4; ++pass) {
                const int idx = (tid + pass * 256) * 4;
                const int row = idx >> 7, col = idx & 127;
                f32x4 v = *(const f32x4*)&cbuf[row * 132 + col];
                *(f32x4*)&Cg[(growbase + row) * 1024 + tileN * 128 + col] = v;
            }
        } else {
            __hip_bfloat16* Cg = (__hip_bfloat16*)Call + cbase;
            #pragma unroll
            for (int pass = 0; pass < 2; ++pass) {
                const int idx = (tid + pass * 256) * 8;
                const int row = idx >> 7, col = idx & 127;
                const float* src = &cbuf[row * 132 + col];
                f32x4 v0 = *(const f32x4*)src;
                f32x4 v1 = *(const f32x4*)(src + 4);
                short8 s;
                #pragma unroll
                for (int i = 0; i < 4; ++i) {
                    s[i] = (short)f2b_raw(v0[i]);
                    s[i + 4] = (short)f2b_raw(v1[i]);
                }
                *(short8*)&Cg[(growbase + row) * 1024 + tileN * 128 + col] = s;
            }
        }
        __syncthreads();
    }
}

extern "C" void kernel_launch(void* const* d_in, const int* in_sizes, int n_in,
                              void* d_out, int out_size, void* d_ws, size_t ws_size,
                              hipStream_t stream)
{
    const float* x  = (const float*)d_in[0];
    const float* qw = (const float*)d_in[1];
    const float* kw = (const float*)d_in[2];
    const float* vw = (const float*)d_in[3];
    const float* rw = (const float*)d_in[4];
    const float* rb = (const float*)d_in[5];
    const float* bg = (const float*)d_in[6];
    const float* bb = (const float*)d_in[7];
    const float* pw = (const float*)d_in[8];
    const float* pb = (const float*)d_in[9];

    float* outF  = (float*)d_out;          // [8,1024,1024] fp32
    float* attnF = outF + 8388608;         // [8,8,1024,1024] fp32

    // workspace (~356 MiB of ~1.15 GiB)
    char* w = (char*)d_ws;
    __hip_bfloat16* qb    = (__hip_bfloat16*)w; w += 16777216;    // [64,1024,128]
    __hip_bfloat16* kb    = (__hip_bfloat16*)w; w += 16777216;
    __hip_bfloat16* vb    = (__hip_bfloat16*)w; w += 16777216;
    __hip_bfloat16* vt    = (__hip_bfloat16*)w; w += 16777216;    // [64,128,1024]
    __hip_bfloat16* Wt    = (__hip_bfloat16*)w; w += 2097152;     // [1024,1024] reatten_w^T
    __hip_bfloat16* pWt   = (__hip_bfloat16*)w; w += 2097152;     // [1024,1024] proj_w^T
    __hip_bfloat16* o2    = (__hip_bfloat16*)w; w += 16777216;    // [8192,1024]
    float*          linv  = (float*)w;          w += 262144;      // [64,1024]
    __hip_bfloat16* Pun   = (__hip_bfloat16*)w; w += 134217728;   // [64,1024,1024]
    __hip_bfloat16* attnb = (__hip_bfloat16*)w; w += 134217728;   // [64,1024,1024]

    conv_qkv<<<8192, 256, 0, stream>>>(x, qw, kw, vw, qb, kb, vb);
    transpose_cast<float><<<dim3(32, 32, 1), 256, 0, stream>>>(rw, Wt, 1024, 1024, 0, 0);
    transpose_cast<float><<<dim3(32, 32, 1), 256, 0, stream>>>(pw, pWt, 1024, 1024, 0, 0);
    transpose_cast<__hip_bfloat16><<<dim3(4, 32, 64), 256, 0, stream>>>(vb, vt, 1024, 128, 131072, 131072);

    // P_un = exp(scale * q k^T), linv = 1/rowsum  (fused QK + softmax)
    qk_softmax<<<dim3(8, 64), 256, 0, stream>>>(qb, kb, Pun, linv);
    // attn = (P_un @ W) * (1/l) * gamma/sqrt(1+eps) + (rb*gamma/sqrt(1+eps) + beta)
    gemm_reatten_256<<<dim3(4, 4, 64), 512, 0, stream>>>(Pun, Wt, attnF, attnb, bg, rb, bb, linv);
    // o2[b, i, h*128+d] = attn @ v
    gemm_nt<2><<<dim3(8, 1, 64), 256, 0, stream>>>(
        attnb, vt, o2, 1024, 1048576, 131072, 0, nullptr);
    // out = o2 @ proj_w + proj_b  (fp32)
    gemm_nt<3><<<dim3(64, 8, 1), 256, 0, stream>>>(
        o2, pWt, outF, 1024, 0, 0, 0, pb);
}